// Round 1
// baseline (14279.456 us; speedup 1.0000x reference)
//
#include <hip/hip_runtime.h>

#define WAVE 64
#define CDIV(a,b) (((a)+(b)-1)/(b))

// ---------- monotonic float<->uint encoding for atomicMax on floats ----------
__device__ __forceinline__ unsigned f2mono(float f) {
    unsigned u = __float_as_uint(f);
    return (u & 0x80000000u) ? ~u : (u | 0x80000000u);
}
__device__ __forceinline__ float mono2f(unsigned u) {
    return (u & 0x80000000u) ? __uint_as_float(u & 0x7fffffffu) : __uint_as_float(~u);
}

// ---------- GEMM: C[M,N] = A[M,K] * B[N,K]^T (row-major, arbitrary ld) ----------
#define GBM 64
#define GBN 64
#define GBK 16
__global__ __launch_bounds__(256)
void k_gemm(const float* __restrict__ A, long lda,
            const float* __restrict__ B, long ldb,
            float* __restrict__ C, long ldc,
            int M, int N, int K)
{
    __shared__ float As[GBK][GBM + 4];
    __shared__ float Bs[GBK][GBN + 4];
    const int tid = threadIdx.x;
    const int tx = tid & 15, ty = tid >> 4;
    const int row0 = blockIdx.y * GBM, col0 = blockIdx.x * GBN;
    float acc[4][4] = {};
    for (int kt = 0; kt < K; kt += GBK) {
        #pragma unroll
        for (int p = 0; p < 4; ++p) {
            int mn = (tid >> 4) + p * 16;   // 0..63
            int k  = tid & 15;
            int gk = kt + k;
            int gr = row0 + mn;
            As[k][mn] = (gr < M && gk < K) ? A[(long)gr * lda + gk] : 0.0f;
            int gc = col0 + mn;
            Bs[k][mn] = (gc < N && gk < K) ? B[(long)gc * ldb + gk] : 0.0f;
        }
        __syncthreads();
        #pragma unroll
        for (int kk = 0; kk < GBK; ++kk) {
            float a0 = As[kk][ty*4+0], a1 = As[kk][ty*4+1];
            float a2 = As[kk][ty*4+2], a3 = As[kk][ty*4+3];
            float b0 = Bs[kk][tx*4+0], b1 = Bs[kk][tx*4+1];
            float b2 = Bs[kk][tx*4+2], b3 = Bs[kk][tx*4+3];
            acc[0][0] += a0*b0; acc[0][1] += a0*b1; acc[0][2] += a0*b2; acc[0][3] += a0*b3;
            acc[1][0] += a1*b0; acc[1][1] += a1*b1; acc[1][2] += a1*b2; acc[1][3] += a1*b3;
            acc[2][0] += a2*b0; acc[2][1] += a2*b1; acc[2][2] += a2*b2; acc[2][3] += a2*b3;
            acc[3][0] += a3*b0; acc[3][1] += a3*b1; acc[3][2] += a3*b2; acc[3][3] += a3*b3;
        }
        __syncthreads();
    }
    #pragma unroll
    for (int i2 = 0; i2 < 4; ++i2)
        #pragma unroll
        for (int j2 = 0; j2 < 4; ++j2) {
            int r = row0 + ty*4 + i2, c = col0 + tx*4 + j2;
            if (r < M && c < N) C[(long)r*ldc + c] = acc[i2][j2];
        }
}

// ---------- degree / dinv ----------
__global__ void k_deg(const int* __restrict__ ii, float* __restrict__ deg, int E) {
    int e = blockIdx.x*blockDim.x + threadIdx.x;
    if (e < E) atomicAdd(&deg[ii[e]], 1.0f);
}
__global__ void k_dinv(float* __restrict__ d, int n) {
    int i = blockIdx.x*blockDim.x + threadIdx.x;
    if (i < n) { float v = d[i]; d[i] = (v > 0.0f) ? 1.0f/sqrtf(v) : 0.0f; }
}

// ---------- GCN aggregation: out[i] += dinv[j]*dinv[i] * xw[j], wave per edge ----------
__global__ void k_gcn_agg(const float* __restrict__ xw, long ldx,
                          const int* __restrict__ jj, const int* __restrict__ ii,
                          const float* __restrict__ dinv,
                          float* __restrict__ out, long ldo, int E, int F)
{
    int w = (blockIdx.x*blockDim.x + threadIdx.x) >> 6;
    int lane = threadIdx.x & 63;
    if (w >= E) return;
    int j = jj[w], i = ii[w];
    float nm = dinv[j]*dinv[i];
    const float4* src = (const float4*)(xw + (long)j*ldx);
    float* dst = out + (long)i*ldo;
    int nf4 = F >> 2;
    for (int f = lane; f < nf4; f += WAVE) {
        float4 v = src[f];
        atomicAdd(&dst[f*4+0], nm*v.x);
        atomicAdd(&dst[f*4+1], nm*v.y);
        atomicAdd(&dst[f*4+2], nm*v.z);
        atomicAdd(&dst[f*4+3], nm*v.w);
    }
}

// ---------- highway combine: out = sig(gl + b)*x2' + (1-sig)*x1 ----------
__global__ void k_highway(const float* __restrict__ x1, long ld1,
                          const float* __restrict__ gl, long ldg,
                          const float* __restrict__ x2, long ld2,
                          const float* __restrict__ bias,
                          float* __restrict__ out, long ldo,
                          long rows, int F, int relu_x2)
{
    long idx = (long)blockIdx.x*blockDim.x + threadIdx.x;
    if (idx >= rows * (long)F) return;
    long r = idx / F; int c = (int)(idx % F);
    float g = 1.0f / (1.0f + expf(-(gl[r*ldg+c] + bias[c])));
    float v2 = x2[r*ld2+c]; if (relu_x2) v2 = fmaxf(v2, 0.0f);
    float v1 = x1[r*ld1+c];
    out[r*ldo+c] = g*v2 + (1.0f-g)*v1;
}

// ---------- segment softmax building blocks ----------
__global__ void k_segmax(const float* __restrict__ ev, const int* __restrict__ idx,
                         unsigned* __restrict__ m, int E) {
    int e = blockIdx.x*blockDim.x + threadIdx.x;
    if (e < E) atomicMax(&m[idx[e]], f2mono(ev[e]));
}
__global__ void k_segsumexp(const float* __restrict__ ev, const int* __restrict__ idx,
                            const unsigned* __restrict__ m, float* __restrict__ s, int E) {
    int e = blockIdx.x*blockDim.x + threadIdx.x;
    if (e < E) atomicAdd(&s[idx[e]], expf(ev[e] - mono2f(m[idx[e]])));
}

// ---------- generic edge score: ev = leaky( sa[ia] (+ sb[ib]) (+ sc[ic % cmod]) ) ----------
__global__ void k_edge_score(const float* __restrict__ sa, const int* __restrict__ ia,
                             const float* __restrict__ sb, const int* __restrict__ ib,
                             const float* __restrict__ sc, const int* __restrict__ ic, int cmod,
                             float* __restrict__ ev, int E)
{
    int e = blockIdx.x*blockDim.x + threadIdx.x;
    if (e >= E) return;
    float v = sa[ia[e]];
    if (sb) v += sb[ib[e]];
    if (sc) v += sc[ic[e] % cmod];
    ev[e] = (v > 0.0f) ? v : 0.01f*v;
}

// ---------- l_gat vsum: vi (keyed i) + vj (keyed j) ----------
__global__ void k_lgat_vsum(const float* __restrict__ val,
                            const int* __restrict__ jj, const int* __restrict__ ii,
                            const unsigned* __restrict__ mi, const float* __restrict__ si,
                            const unsigned* __restrict__ mj, const float* __restrict__ sj,
                            float* __restrict__ vsum, int E)
{
    int e = blockIdx.x*blockDim.x + threadIdx.x;
    if (e >= E) return;
    float v = val[e];
    int i = ii[e], j = jj[e];
    float pi = expf(v - mono2f(mi[i])) / (si[i] + 1e-16f);
    float pj = expf(v - mono2f(mj[j])) / (sj[j] + 1e-16f);
    vsum[e] = pi + pj;
}

// ---------- generic softmax-weighted aggregation, wave per edge ----------
// alpha = exp(ev - m[ka]) / (s[ka]+eps);  out[ko] += alpha * x[ks]
__global__ void k_edge_agg(const float* __restrict__ ev,
                           const unsigned* __restrict__ m, const float* __restrict__ s,
                           const int* __restrict__ ka, const int* __restrict__ ko,
                           const int* __restrict__ ks,
                           const float* __restrict__ x, long ldx,
                           float* __restrict__ out, long ldo,
                           int E, int F)
{
    int w = (blockIdx.x*blockDim.x + threadIdx.x) >> 6;
    int lane = threadIdx.x & 63;
    if (w >= E) return;
    int a = ka[w];
    float alpha = expf(ev[w] - mono2f(m[a])) / (s[a] + 1e-16f);
    const float4* src = (const float4*)(x + (long)ks[w]*ldx);
    float* dst = out + (long)ko[w]*ldo;
    int nf4 = F >> 2;
    for (int f = lane; f < nf4; f += WAVE) {
        float4 v = src[f];
        atomicAdd(&dst[f*4+0], alpha*v.x);
        atomicAdd(&dst[f*4+1], alpha*v.y);
        atomicAdd(&dst[f*4+2], alpha*v.z);
        atomicAdd(&dst[f*4+3], alpha*v.w);
    }
}

// ---------- strided zero / relu ----------
__global__ void k_zero2d(float* __restrict__ p, long rows, int cols, long ld) {
    long idx = (long)blockIdx.x*blockDim.x + threadIdx.x;
    if (idx >= rows*(long)cols) return;
    long r = idx / cols; int c = (int)(idx % cols);
    p[r*ld+c] = 0.0f;
}
__global__ void k_relu2d(float* __restrict__ p, long rows, int cols, long ld) {
    long idx = (long)blockIdx.x*blockDim.x + threadIdx.x;
    if (idx >= rows*(long)cols) return;
    long r = idx / cols; int c = (int)(idx % cols);
    float v = p[r*ld+c];
    p[r*ld+c] = fmaxf(v, 0.0f);
}

// ---------- row dots: oa[r] = x[r]·a, ob[r] = x[r]·b  (wave per row) ----------
__global__ void k_rowdot2(const float* __restrict__ x, long ldx, int rows, int K,
                          const float* __restrict__ a, const float* __restrict__ b,
                          float* __restrict__ oa, float* __restrict__ ob)
{
    int w = (blockIdx.x*blockDim.x + threadIdx.x) >> 6;
    int lane = threadIdx.x & 63;
    if (w >= rows) return;
    const float* xr = x + (long)w*ldx;
    float sa = 0.0f, sb = 0.0f;
    for (int k = lane; k < K; k += WAVE) {
        float v = xr[k];
        sa += v * a[k];
        if (b) sb += v * b[k];
    }
    #pragma unroll
    for (int off = 32; off > 0; off >>= 1) {
        sa += __shfl_down(sa, off);
        if (b) sb += __shfl_down(sb, off);
    }
    if (lane == 0) { oa[w] = sa; if (ob) ob[w] = sb; }
}

// ---------- relscore[r] = merge[r]·ar[0:RH] + tri[r]·ar[RH:2RH] ----------
__global__ void k_relscore(const float* __restrict__ mg, const float* __restrict__ tr,
                           const float* __restrict__ ar, float* __restrict__ out, int R, int RH)
{
    int w = (blockIdx.x*blockDim.x + threadIdx.x) >> 6;
    int lane = threadIdx.x & 63;
    if (w >= R) return;
    float s = 0.0f;
    for (int k = lane; k < RH; k += WAVE)
        s += mg[(long)w*RH+k]*ar[k] + tr[(long)w*RH+k]*ar[RH+k];
    #pragma unroll
    for (int off = 32; off > 0; off >>= 1) s += __shfl_down(s, off);
    if (lane == 0) out[w] = s;
}

extern "C" void kernel_launch(void* const* d_in, const int* in_sizes, int n_in,
                              void* d_out, int out_size, void* d_ws, size_t ws_size,
                              hipStream_t stream)
{
    const float* x_e   = (const float*)d_in[0];
    const float* mval  = (const float*)d_in[1];
    const float* tval  = (const float*)d_in[2];
    const float* g1w   = (const float*)d_in[3];
    const float* h1w   = (const float*)d_in[4];
    const float* h1b   = (const float*)d_in[5];
    const float* g2w   = (const float*)d_in[6];
    const float* h2w   = (const float*)d_in[7];
    const float* h2b   = (const float*)d_in[8];
    const float* remb1 = (const float*)d_in[9];
    const float* remb2 = (const float*)d_in[10];
    const float* hrw   = (const float*)d_in[11];
    const float* hrb   = (const float*)d_in[12];
    const float* gat_ai= (const float*)d_in[13];
    const float* gat_aj= (const float*)d_in[14];
    const float* gat_ar= (const float*)d_in[15];
    const float* g2e_ah= (const float*)d_in[16];
    const float* g2e_at= (const float*)d_in[17];
    const float* g2e_ar= (const float*)d_in[18];
    const int* edge_index     = (const int*)d_in[19];
    const int* rel            = (const int*)d_in[20];
    const int* edge_index_all = (const int*)d_in[21];
    const int* rel_all        = (const int*)d_in[22];
    const int* lg_merge       = (const int*)d_in[23];
    const int* lg_tri         = (const int*)d_in[24];

    const int F    = 300;
    const int RH   = 100;
    const int N    = in_sizes[0] / F;      // 100000
    const int E    = in_sizes[20];         // 400000
    const int EA   = in_sizes[22];         // 800000
    const int LGE  = in_sizes[1];          // 60000
    const int R    = in_sizes[9] / RH;     // 2000
    const long OUTC = 800;

    const int* jA = edge_index_all;        // ei[0] = j (source)
    const int* iA = edge_index_all + EA;   // ei[1] = i (dest)
    const int* hE = edge_index;            // ei[0] = h
    const int* tE = edge_index + E;        // ei[1] = t
    const int* jM = lg_merge;  const int* iM = lg_merge + LGE;
    const int* jT = lg_tri;    const int* iT = lg_tri  + LGE;

    float* ws = (float*)d_ws;
    size_t off = 0;
    auto alloc = [&](size_t n) { float* p = ws + off; off += n; return p; };
    float*    A    = alloc((size_t)N*F);     // GEMM scratch [N,300]
    float*    dinv = alloc(N);
    unsigned* m1   = (unsigned*)alloc(N);
    float*    s1   = alloc(N);
    unsigned* m2   = (unsigned*)alloc(N);
    float*    s2   = alloc(N);
    float*    ev   = alloc(EA);              // edge scores (EA, or 2x E halves)
    float*    sA_  = alloc(N);               // si / sh
    float*    sB_  = alloc(N);               // sj / st
    float*    mrg  = alloc((size_t)R*RH);
    float*    tri  = alloc((size_t)R*RH);
    float*    xr   = alloc((size_t)R*RH);
    float*    xrg  = alloc((size_t)R*RH);
    unsigned* lmi  = (unsigned*)alloc(R);  float* lsi = alloc(R);
    unsigned* lmj  = (unsigned*)alloc(R);  float* lsj = alloc(R);
    unsigned* lm2  = (unsigned*)alloc(R);  float* ls2 = alloc(R);
    float*    vsum = alloc(LGE);
    float*    rsc  = alloc(R);
    float*    srel = alloc(R);

    float* out = (float*)d_out;              // [N, 800]

    const long NF = (long)N * F;
    dim3 gemmGrid(CDIV(F,GBN), CDIV(N,GBM));

    // ===== degrees (shared by both GCN layers) =====
    hipMemsetAsync(dinv, 0, N*sizeof(float), stream);
    k_deg<<<CDIV(EA,256),256,0,stream>>>(iA, dinv, EA);
    k_dinv<<<CDIV(N,256),256,0,stream>>>(dinv, N);

    // ===== GCN layer 1 + highway  (agg scratch = out cols 300..599) =====
    k_gemm<<<gemmGrid,256,0,stream>>>(x_e, F, g1w, F, A, F, N, F, F);
    k_zero2d<<<CDIV(NF,256),256,0,stream>>>(out+300, N, F, OUTC);
    k_gcn_agg<<<(int)CDIV((long)EA*64,256),256,0,stream>>>(A, F, jA, iA, dinv, out+300, OUTC, EA, F);
    k_gemm<<<gemmGrid,256,0,stream>>>(x_e, F, h1w, F, A, F, N, F, F);
    k_highway<<<CDIV(NF,256),256,0,stream>>>(x_e, F, A, F, out+300, OUTC, h1b, out, OUTC, N, F, 1);

    // ===== GCN layer 2 + highway (h1 lives in out cols 0..299) =====
    k_gemm<<<gemmGrid,256,0,stream>>>(out, OUTC, g2w, F, A, F, N, F, F);
    k_zero2d<<<CDIV(NF,256),256,0,stream>>>(out+300, N, F, OUTC);
    k_gcn_agg<<<(int)CDIV((long)EA*64,256),256,0,stream>>>(A, F, jA, iA, dinv, out+300, OUTC, EA, F);
    k_gemm<<<gemmGrid,256,0,stream>>>(out, OUTC, h2w, F, A, F, N, F, F);
    k_highway<<<CDIV(NF,256),256,0,stream>>>(out, OUTC, A, F, out+300, OUTC, h2b, out, OUTC, N, F, 1);

    // ===== l_gat on the two line graphs =====
    auto lgat = [&](const float* xrel, const int* jjE, const int* iiE, const float* val, float* obuf) {
        hipMemsetAsync(lmi, 0, R*4, stream); hipMemsetAsync(lsi, 0, R*4, stream);
        hipMemsetAsync(lmj, 0, R*4, stream); hipMemsetAsync(lsj, 0, R*4, stream);
        hipMemsetAsync(lm2, 0, R*4, stream); hipMemsetAsync(ls2, 0, R*4, stream);
        hipMemsetAsync(obuf, 0, (size_t)R*RH*4, stream);
        k_segmax   <<<CDIV(LGE,256),256,0,stream>>>(val, iiE, lmi, LGE);
        k_segmax   <<<CDIV(LGE,256),256,0,stream>>>(val, jjE, lmj, LGE);
        k_segsumexp<<<CDIV(LGE,256),256,0,stream>>>(val, iiE, lmi, lsi, LGE);
        k_segsumexp<<<CDIV(LGE,256),256,0,stream>>>(val, jjE, lmj, lsj, LGE);
        k_lgat_vsum<<<CDIV(LGE,256),256,0,stream>>>(val, jjE, iiE, lmi, lsi, lmj, lsj, vsum, LGE);
        k_segmax   <<<CDIV(LGE,256),256,0,stream>>>(vsum, jjE, lm2, LGE);
        k_segsumexp<<<CDIV(LGE,256),256,0,stream>>>(vsum, jjE, lm2, ls2, LGE);
        k_edge_agg <<<(int)CDIV((long)LGE*64,256),256,0,stream>>>(vsum, lm2, ls2, jjE, iiE, jjE,
                                                                  xrel, RH, obuf, RH, LGE, RH);
        k_relu2d   <<<CDIV((long)R*RH,256),256,0,stream>>>(obuf, R, RH, RH);
    };
    lgat(remb1, jM, iM, mval, mrg);
    lgat(remb2, jT, iT, tval, tri);

    // ===== x_r = highway(mrg, tri, hrw, hrb) =====
    dim3 gridR(CDIV(RH,GBN), CDIV(R,GBM));
    k_gemm<<<gridR,256,0,stream>>>(mrg, RH, hrw, RH, xrg, RH, R, RH, RH);
    k_highway<<<CDIV((long)R*RH,256),256,0,stream>>>(mrg, RH, xrg, RH, tri, RH, hrb, xr, RH, R, RH, 0);

    // relscore[r] = rel_cat[r]·gat_ar  (rel_emb row k == rel_cat[k % R])
    k_relscore<<<CDIV((long)R*64,256),256,0,stream>>>(mrg, tri, gat_ar, rsc, R, RH);

    // ===== GAT over edge_index_all -> out cols 300..599 =====
    k_rowdot2<<<CDIV((long)N*64,256),256,0,stream>>>(out, OUTC, N, F, gat_ai, gat_aj, sA_, sB_);
    k_edge_score<<<CDIV(EA,256),256,0,stream>>>(sA_, iA, sB_, jA, rsc, rel_all, R, ev, EA);
    hipMemsetAsync(m1, 0, N*4, stream); hipMemsetAsync(s1, 0, N*4, stream);
    k_segmax   <<<CDIV(EA,256),256,0,stream>>>(ev, iA, m1, EA);
    k_segsumexp<<<CDIV(EA,256),256,0,stream>>>(ev, iA, m1, s1, EA);
    k_zero2d<<<CDIV(NF,256),256,0,stream>>>(out+300, N, F, OUTC);
    k_edge_agg<<<(int)CDIV((long)EA*64,256),256,0,stream>>>(ev, m1, s1, iA, iA, jA,
                                                            out, OUTC, out+300, OUTC, EA, F);
    k_relu2d<<<CDIV(NF,256),256,0,stream>>>(out+300, N, F, OUTC);

    // ===== gat_r_to_e over edge_index -> out cols 600..799 =====
    k_rowdot2<<<CDIV((long)N*64,256),256,0,stream>>>(out, OUTC, N, 2*F, g2e_ah, g2e_at, sA_, sB_);
    k_rowdot2<<<CDIV((long)R*64,256),256,0,stream>>>(xr, RH, R, RH, g2e_ar, (const float*)nullptr,
                                                     srel, (float*)nullptr);
    float* evh = ev;
    float* evt = ev + E;
    k_edge_score<<<CDIV(E,256),256,0,stream>>>(sA_, hE, (const float*)nullptr, (const int*)nullptr,
                                               srel, rel, R, evh, E);
    k_edge_score<<<CDIV(E,256),256,0,stream>>>(sB_, tE, (const float*)nullptr, (const int*)nullptr,
                                               srel, rel, R, evt, E);
    hipMemsetAsync(m1, 0, N*4, stream); hipMemsetAsync(s1, 0, N*4, stream);
    hipMemsetAsync(m2, 0, N*4, stream); hipMemsetAsync(s2, 0, N*4, stream);
    k_segmax   <<<CDIV(E,256),256,0,stream>>>(evh, hE, m1, E);
    k_segsumexp<<<CDIV(E,256),256,0,stream>>>(evh, hE, m1, s1, E);
    k_segmax   <<<CDIV(E,256),256,0,stream>>>(evt, tE, m2, E);
    k_segsumexp<<<CDIV(E,256),256,0,stream>>>(evt, tE, m2, s2, E);
    k_zero2d<<<CDIV((long)N*200,256),256,0,stream>>>(out+600, N, 200, OUTC);
    k_edge_agg<<<(int)CDIV((long)E*64,256),256,0,stream>>>(evh, m1, s1, hE, hE, rel,
                                                           xr, RH, out+600, OUTC, E, RH);
    k_edge_agg<<<(int)CDIV((long)E*64,256),256,0,stream>>>(evt, m2, s2, tE, tE, rel,
                                                           xr, RH, out+700, OUTC, E, RH);
}

// Round 2
// 3684.730 us; speedup vs baseline: 3.8753x; 3.8753x over previous
//
#include <hip/hip_runtime.h>

#define WAVE 64
#define CDIV(a,b) (((a)+(b)-1)/(b))

// ---------- monotonic float<->uint encoding for atomicMax on floats ----------
__device__ __forceinline__ unsigned f2mono(float f) {
    unsigned u = __float_as_uint(f);
    return (u & 0x80000000u) ? ~u : (u | 0x80000000u);
}
__device__ __forceinline__ float mono2f(unsigned u) {
    return (u & 0x80000000u) ? __uint_as_float(u & 0x7fffffffu) : __uint_as_float(~u);
}

// ---------- GEMM: C[M,N] = A[M,K] * B[N,K]^T (row-major, arbitrary ld) ----------
#define GBM 64
#define GBN 64
#define GBK 16
__global__ __launch_bounds__(256)
void k_gemm(const float* __restrict__ A, long lda,
            const float* __restrict__ B, long ldb,
            float* __restrict__ C, long ldc,
            int M, int N, int K)
{
    __shared__ float As[GBK][GBM + 4];
    __shared__ float Bs[GBK][GBN + 4];
    const int tid = threadIdx.x;
    const int tx = tid & 15, ty = tid >> 4;
    const int row0 = blockIdx.y * GBM, col0 = blockIdx.x * GBN;
    float acc[4][4] = {};
    for (int kt = 0; kt < K; kt += GBK) {
        #pragma unroll
        for (int p = 0; p < 4; ++p) {
            int mn = (tid >> 4) + p * 16;   // 0..63
            int k  = tid & 15;
            int gk = kt + k;
            int gr = row0 + mn;
            As[k][mn] = (gr < M && gk < K) ? A[(long)gr * lda + gk] : 0.0f;
            int gc = col0 + mn;
            Bs[k][mn] = (gc < N && gk < K) ? B[(long)gc * ldb + gk] : 0.0f;
        }
        __syncthreads();
        #pragma unroll
        for (int kk = 0; kk < GBK; ++kk) {
            float a0 = As[kk][ty*4+0], a1 = As[kk][ty*4+1];
            float a2 = As[kk][ty*4+2], a3 = As[kk][ty*4+3];
            float b0 = Bs[kk][tx*4+0], b1 = Bs[kk][tx*4+1];
            float b2 = Bs[kk][tx*4+2], b3 = Bs[kk][tx*4+3];
            acc[0][0] += a0*b0; acc[0][1] += a0*b1; acc[0][2] += a0*b2; acc[0][3] += a0*b3;
            acc[1][0] += a1*b0; acc[1][1] += a1*b1; acc[1][2] += a1*b2; acc[1][3] += a1*b3;
            acc[2][0] += a2*b0; acc[2][1] += a2*b1; acc[2][2] += a2*b2; acc[2][3] += a2*b3;
            acc[3][0] += a3*b0; acc[3][1] += a3*b1; acc[3][2] += a3*b2; acc[3][3] += a3*b3;
        }
        __syncthreads();
    }
    #pragma unroll
    for (int i2 = 0; i2 < 4; ++i2)
        #pragma unroll
        for (int j2 = 0; j2 < 4; ++j2) {
            int r = row0 + ty*4 + i2, c = col0 + tx*4 + j2;
            if (r < M && c < N) C[(long)r*ldc + c] = acc[i2][j2];
        }
}

// ================= CSR build: histogram -> scan -> fill =================
__global__ void k_hist(const int* __restrict__ key, int* __restrict__ cnt, int E) {
    int e = blockIdx.x*blockDim.x + threadIdx.x;
    if (e < E) atomicAdd(&cnt[key[e]], 1);
}
__global__ void k_scan1(const int* __restrict__ in, int* __restrict__ out,
                        int* __restrict__ bsum, int n) {
    __shared__ int sh[256];
    int gid = blockIdx.x*256 + threadIdx.x;
    int v = (gid < n) ? in[gid] : 0;
    sh[threadIdx.x] = v; __syncthreads();
    for (int o = 1; o < 256; o <<= 1) {
        int t = (threadIdx.x >= o) ? sh[threadIdx.x - o] : 0;
        __syncthreads();
        sh[threadIdx.x] += t;
        __syncthreads();
    }
    if (gid < n) out[gid] = sh[threadIdx.x] - v;      // exclusive
    if (threadIdx.x == 255) bsum[blockIdx.x] = sh[255];
}
__global__ void k_scan2(int* __restrict__ bsum, int nb) {   // single block, nb <= 1024
    __shared__ int sh[1024];
    int v = (threadIdx.x < nb) ? bsum[threadIdx.x] : 0;
    sh[threadIdx.x] = v; __syncthreads();
    for (int o = 1; o < 1024; o <<= 1) {
        int t = (threadIdx.x >= o) ? sh[threadIdx.x - o] : 0;
        __syncthreads();
        sh[threadIdx.x] += t;
        __syncthreads();
    }
    if (threadIdx.x < nb) bsum[threadIdx.x] = sh[threadIdx.x] - v;  // exclusive
}
__global__ void k_scan3(int* __restrict__ out, const int* __restrict__ bsum, int n) {
    int gid = blockIdx.x*256 + threadIdx.x;
    if (gid < n) out[gid] += bsum[blockIdx.x];
}
__global__ void k_fill(const int* __restrict__ key, const int* __restrict__ rowptr,
                       int* __restrict__ cursor, int* __restrict__ perm, int E) {
    int e = blockIdx.x*blockDim.x + threadIdx.x;
    if (e >= E) return;
    int k = key[e];
    int p = rowptr[k] + atomicAdd(&cursor[k], 1);
    perm[p] = e;
}

__global__ void k_dinv_cnt(const int* __restrict__ cnt, float* __restrict__ dinv, int n) {
    int i = blockIdx.x*blockDim.x + threadIdx.x;
    if (i < n) { int c = cnt[i]; dinv[i] = (c > 0) ? rsqrtf((float)c) : 0.0f; }
}

// ============ gather aggregations (wave per destination node) ============
// GCN: out[w,:] = sum_{e in seg(w)} dinv[w]*dinv[j_e] * x[j_e,:]
template<int NC>
__global__ void k_gather_norm(const float* __restrict__ x, long ldx,
                              const int* __restrict__ srcj,
                              const int* __restrict__ rowptr, const int* __restrict__ cnt,
                              const int* __restrict__ perm,
                              const float* __restrict__ dinv,
                              float* __restrict__ out, long ldo, int n, int F)
{
    int w = (blockIdx.x*blockDim.x + threadIdx.x) >> 6;
    int lane = threadIdx.x & 63;
    if (w >= n) return;
    int beg = rowptr[w], end = beg + cnt[w];
    float di = dinv[w];
    float acc[NC] = {};
    for (int e = beg; e < end; ++e) {
        int ed = perm[e];
        int j = srcj[ed];
        float nm = di * dinv[j];
        const float* xr = x + (long)j*ldx;
        #pragma unroll
        for (int q = 0; q < NC; ++q) { int f = lane + q*64; if (f < F) acc[q] += nm * xr[f]; }
    }
    float* dst = out + (long)w*ldo;
    #pragma unroll
    for (int q = 0; q < NC; ++q) { int f = lane + q*64; if (f < F) dst[f] = acc[q]; }
}

// softmax-weighted gather with fused segment softmax (softmax key == output key)
template<int NC>
__global__ void k_gather_soft(const float* __restrict__ x, long ldx,
                              const float* __restrict__ ev,
                              const int* __restrict__ srcidx,
                              const int* __restrict__ rowptr, const int* __restrict__ cnt,
                              const int* __restrict__ perm,
                              float* __restrict__ out, long ldo, int n, int F, int relu)
{
    int w = (blockIdx.x*blockDim.x + threadIdx.x) >> 6;
    int lane = threadIdx.x & 63;
    if (w >= n) return;
    int beg = rowptr[w], c = cnt[w], end = beg + c;
    float acc[NC] = {};
    if (c > 0) {
        float mx = -3.4e38f;
        for (int e = beg; e < end; ++e) mx = fmaxf(mx, ev[perm[e]]);
        float ss = 0.0f;
        for (int e = beg; e < end; ++e) ss += expf(ev[perm[e]] - mx);
        float inv = 1.0f / (ss + 1e-16f);
        for (int e = beg; e < end; ++e) {
            int ed = perm[e];
            float alpha = expf(ev[ed] - mx) * inv;
            const float* xr = x + (long)srcidx[ed]*ldx;
            #pragma unroll
            for (int q = 0; q < NC; ++q) { int f = lane + q*64; if (f < F) acc[q] += alpha * xr[f]; }
        }
    }
    float* dst = out + (long)w*ldo;
    #pragma unroll
    for (int q = 0; q < NC; ++q) {
        int f = lane + q*64;
        if (f < F) dst[f] = relu ? fmaxf(acc[q], 0.0f) : acc[q];
    }
}

// ---------- highway combine: out = sig(gl + b)*x2' + (1-sig)*x1 ----------
__global__ void k_highway(const float* __restrict__ x1, long ld1,
                          const float* __restrict__ gl, long ldg,
                          const float* __restrict__ x2, long ld2,
                          const float* __restrict__ bias,
                          float* __restrict__ out, long ldo,
                          long rows, int F, int relu_x2)
{
    long idx = (long)blockIdx.x*blockDim.x + threadIdx.x;
    if (idx >= rows * (long)F) return;
    long r = idx / F; int c = (int)(idx % F);
    float g = 1.0f / (1.0f + expf(-(gl[r*ldg+c] + bias[c])));
    float v2 = x2[r*ld2+c]; if (relu_x2) v2 = fmaxf(v2, 0.0f);
    float v1 = x1[r*ld1+c];
    out[r*ldo+c] = g*v2 + (1.0f-g)*v1;
}

// ---------- segment softmax building blocks (small l_gat path only) ----------
__global__ void k_segmax(const float* __restrict__ ev, const int* __restrict__ idx,
                         unsigned* __restrict__ m, int E) {
    int e = blockIdx.x*blockDim.x + threadIdx.x;
    if (e < E) atomicMax(&m[idx[e]], f2mono(ev[e]));
}
__global__ void k_segsumexp(const float* __restrict__ ev, const int* __restrict__ idx,
                            const unsigned* __restrict__ m, float* __restrict__ s, int E) {
    int e = blockIdx.x*blockDim.x + threadIdx.x;
    if (e < E) atomicAdd(&s[idx[e]], expf(ev[e] - mono2f(m[idx[e]])));
}

// ---------- generic edge score: ev = leaky( sa[ia] (+ sb[ib]) (+ sc[ic % cmod]) ) ----------
__global__ void k_edge_score(const float* __restrict__ sa, const int* __restrict__ ia,
                             const float* __restrict__ sb, const int* __restrict__ ib,
                             const float* __restrict__ sc, const int* __restrict__ ic, int cmod,
                             float* __restrict__ ev, int E)
{
    int e = blockIdx.x*blockDim.x + threadIdx.x;
    if (e >= E) return;
    float v = sa[ia[e]];
    if (sb) v += sb[ib[e]];
    if (sc) v += sc[ic[e] % cmod];
    ev[e] = (v > 0.0f) ? v : 0.01f*v;
}

// ---------- l_gat vsum ----------
__global__ void k_lgat_vsum(const float* __restrict__ val,
                            const int* __restrict__ jj, const int* __restrict__ ii,
                            const unsigned* __restrict__ mi, const float* __restrict__ si,
                            const unsigned* __restrict__ mj, const float* __restrict__ sj,
                            float* __restrict__ vsum, int E)
{
    int e = blockIdx.x*blockDim.x + threadIdx.x;
    if (e >= E) return;
    float v = val[e];
    int i = ii[e], j = jj[e];
    float pi = expf(v - mono2f(mi[i])) / (si[i] + 1e-16f);
    float pj = expf(v - mono2f(mj[j])) / (sj[j] + 1e-16f);
    vsum[e] = pi + pj;
}

// ---------- atomic softmax-weighted scatter (l_gat only; key_a != key_out) ----------
__global__ void k_edge_agg(const float* __restrict__ ev,
                           const unsigned* __restrict__ m, const float* __restrict__ s,
                           const int* __restrict__ ka, const int* __restrict__ ko,
                           const int* __restrict__ ks,
                           const float* __restrict__ x, long ldx,
                           float* __restrict__ out, long ldo,
                           int E, int F)
{
    int w = (blockIdx.x*blockDim.x + threadIdx.x) >> 6;
    int lane = threadIdx.x & 63;
    if (w >= E) return;
    int a = ka[w];
    float alpha = expf(ev[w] - mono2f(m[a])) / (s[a] + 1e-16f);
    const float4* src = (const float4*)(x + (long)ks[w]*ldx);
    float* dst = out + (long)ko[w]*ldo;
    int nf4 = F >> 2;
    for (int f = lane; f < nf4; f += WAVE) {
        float4 v = src[f];
        atomicAdd(&dst[f*4+0], alpha*v.x);
        atomicAdd(&dst[f*4+1], alpha*v.y);
        atomicAdd(&dst[f*4+2], alpha*v.z);
        atomicAdd(&dst[f*4+3], alpha*v.w);
    }
}

__global__ void k_relu2d(float* __restrict__ p, long rows, int cols, long ld) {
    long idx = (long)blockIdx.x*blockDim.x + threadIdx.x;
    if (idx >= rows*(long)cols) return;
    long r = idx / cols; int c = (int)(idx % cols);
    float v = p[r*ld+c];
    p[r*ld+c] = fmaxf(v, 0.0f);
}

// ---------- row dots: oa[r] = x[r]·a, ob[r] = x[r]·b  (wave per row) ----------
__global__ void k_rowdot2(const float* __restrict__ x, long ldx, int rows, int K,
                          const float* __restrict__ a, const float* __restrict__ b,
                          float* __restrict__ oa, float* __restrict__ ob)
{
    int w = (blockIdx.x*blockDim.x + threadIdx.x) >> 6;
    int lane = threadIdx.x & 63;
    if (w >= rows) return;
    const float* xr = x + (long)w*ldx;
    float sa = 0.0f, sb = 0.0f;
    for (int k = lane; k < K; k += WAVE) {
        float v = xr[k];
        sa += v * a[k];
        if (b) sb += v * b[k];
    }
    #pragma unroll
    for (int off = 32; off > 0; off >>= 1) {
        sa += __shfl_down(sa, off);
        if (b) sb += __shfl_down(sb, off);
    }
    if (lane == 0) { oa[w] = sa; if (ob) ob[w] = sb; }
}

// ---------- relscore[r] = merge[r]·ar[0:RH] + tri[r]·ar[RH:2RH] ----------
__global__ void k_relscore(const float* __restrict__ mg, const float* __restrict__ tr,
                           const float* __restrict__ ar, float* __restrict__ out, int R, int RH)
{
    int w = (blockIdx.x*blockDim.x + threadIdx.x) >> 6;
    int lane = threadIdx.x & 63;
    if (w >= R) return;
    float s = 0.0f;
    for (int k = lane; k < RH; k += WAVE)
        s += mg[(long)w*RH+k]*ar[k] + tr[(long)w*RH+k]*ar[RH+k];
    #pragma unroll
    for (int off = 32; off > 0; off >>= 1) s += __shfl_down(s, off);
    if (lane == 0) out[w] = s;
}

extern "C" void kernel_launch(void* const* d_in, const int* in_sizes, int n_in,
                              void* d_out, int out_size, void* d_ws, size_t ws_size,
                              hipStream_t stream)
{
    const float* x_e   = (const float*)d_in[0];
    const float* mval  = (const float*)d_in[1];
    const float* tval  = (const float*)d_in[2];
    const float* g1w   = (const float*)d_in[3];
    const float* h1w   = (const float*)d_in[4];
    const float* h1b   = (const float*)d_in[5];
    const float* g2w   = (const float*)d_in[6];
    const float* h2w   = (const float*)d_in[7];
    const float* h2b   = (const float*)d_in[8];
    const float* remb1 = (const float*)d_in[9];
    const float* remb2 = (const float*)d_in[10];
    const float* hrw   = (const float*)d_in[11];
    const float* hrb   = (const float*)d_in[12];
    const float* gat_ai= (const float*)d_in[13];
    const float* gat_aj= (const float*)d_in[14];
    const float* gat_ar= (const float*)d_in[15];
    const float* g2e_ah= (const float*)d_in[16];
    const float* g2e_at= (const float*)d_in[17];
    const float* g2e_ar= (const float*)d_in[18];
    const int* edge_index     = (const int*)d_in[19];
    const int* rel            = (const int*)d_in[20];
    const int* edge_index_all = (const int*)d_in[21];
    const int* rel_all        = (const int*)d_in[22];
    const int* lg_merge       = (const int*)d_in[23];
    const int* lg_tri         = (const int*)d_in[24];

    const int F    = 300;
    const int RH   = 100;
    const int N    = in_sizes[0] / F;      // 100000
    const int E    = in_sizes[20];         // 400000
    const int EA   = in_sizes[22];         // 800000
    const int LGE  = in_sizes[1];          // 60000
    const int R    = in_sizes[9] / RH;     // 2000
    const long OUTC = 800;

    const int* jA = edge_index_all;        // ei[0] = j (source)
    const int* iA = edge_index_all + EA;   // ei[1] = i (dest)
    const int* hE = edge_index;            // ei[0] = h
    const int* tE = edge_index + E;        // ei[1] = t
    const int* jM = lg_merge;  const int* iM = lg_merge + LGE;
    const int* jT = lg_tri;    const int* iT = lg_tri  + LGE;

    float* ws = (float*)d_ws;
    size_t off = 0;
    auto alloc = [&](size_t n) { float* p = ws + off; off += n; return p; };
    float*    A    = alloc((size_t)N*F);     // GEMM scratch [N,300]
    float*    dinv = alloc(N);
    float*    ev   = alloc(EA);
    float*    sA_  = alloc(N);
    float*    sB_  = alloc(N);
    float*    mrg  = alloc((size_t)R*RH);
    float*    tri  = alloc((size_t)R*RH);
    float*    xr   = alloc((size_t)R*RH);
    float*    xrg  = alloc((size_t)R*RH);
    unsigned* lmi  = (unsigned*)alloc(R);  float* lsi = alloc(R);
    unsigned* lmj  = (unsigned*)alloc(R);  float* lsj = alloc(R);
    unsigned* lm2  = (unsigned*)alloc(R);  float* ls2 = alloc(R);
    float*    vsum = alloc(LGE);
    float*    rsc  = alloc(R);
    float*    srel = alloc(R);
    // CSR structures
    int* bsum    = (int*)alloc(1024);
    int* cursor  = (int*)alloc(N);
    int* rowptrA = (int*)alloc(N); int* cntA = (int*)alloc(N); int* permA = (int*)alloc(EA);
    int* rowptrH = (int*)alloc(N); int* cntH = (int*)alloc(N); int* permH = (int*)alloc(E);
    int* rowptrT = (int*)alloc(N); int* cntT = (int*)alloc(N); int* permT = (int*)alloc(E);

    float* out = (float*)d_out;              // [N, 800]

    const long NF = (long)N * F;
    const int  nb = CDIV(N, 256);            // 391 <= 1024
    dim3 gemmGrid(CDIV(F,GBN), CDIV(N,GBM));
    const int gatherGrid = CDIV(N, 4);       // wave per node, 4 waves/block

    auto build_csr = [&](const int* key, int E_, int* rowptr, int* cnt, int* perm) {
        hipMemsetAsync(cnt, 0, (size_t)N*4, stream);
        k_hist<<<CDIV(E_,256),256,0,stream>>>(key, cnt, E_);
        k_scan1<<<nb,256,0,stream>>>(cnt, rowptr, bsum, N);
        k_scan2<<<1,1024,0,stream>>>(bsum, nb);
        k_scan3<<<nb,256,0,stream>>>(rowptr, bsum, N);
        hipMemsetAsync(cursor, 0, (size_t)N*4, stream);
        k_fill<<<CDIV(E_,256),256,0,stream>>>(key, rowptr, cursor, perm, E_);
    };

    // ===== CSRs (dest-keyed for GCN/GAT; h/t-keyed for r2e) =====
    build_csr(iA, EA, rowptrA, cntA, permA);
    build_csr(hE, E,  rowptrH, cntH, permH);
    build_csr(tE, E,  rowptrT, cntT, permT);
    k_dinv_cnt<<<CDIV(N,256),256,0,stream>>>(cntA, dinv, N);

    // ===== GCN layer 1 + highway (agg scratch = out cols 300..599) =====
    k_gemm<<<gemmGrid,256,0,stream>>>(x_e, F, g1w, F, A, F, N, F, F);
    k_gather_norm<5><<<gatherGrid,256,0,stream>>>(A, F, jA, rowptrA, cntA, permA, dinv,
                                                  out+300, OUTC, N, F);
    k_gemm<<<gemmGrid,256,0,stream>>>(x_e, F, h1w, F, A, F, N, F, F);
    k_highway<<<CDIV(NF,256),256,0,stream>>>(x_e, F, A, F, out+300, OUTC, h1b, out, OUTC, N, F, 1);

    // ===== GCN layer 2 + highway (h1 lives in out cols 0..299) =====
    k_gemm<<<gemmGrid,256,0,stream>>>(out, OUTC, g2w, F, A, F, N, F, F);
    k_gather_norm<5><<<gatherGrid,256,0,stream>>>(A, F, jA, rowptrA, cntA, permA, dinv,
                                                  out+300, OUTC, N, F);
    k_gemm<<<gemmGrid,256,0,stream>>>(out, OUTC, h2w, F, A, F, N, F, F);
    k_highway<<<CDIV(NF,256),256,0,stream>>>(out, OUTC, A, F, out+300, OUTC, h2b, out, OUTC, N, F, 1);

    // ===== l_gat on the two line graphs (small; atomic path) =====
    auto lgat = [&](const float* xrel, const int* jjE, const int* iiE, const float* val, float* obuf) {
        hipMemsetAsync(lmi, 0, R*4, stream); hipMemsetAsync(lsi, 0, R*4, stream);
        hipMemsetAsync(lmj, 0, R*4, stream); hipMemsetAsync(lsj, 0, R*4, stream);
        hipMemsetAsync(lm2, 0, R*4, stream); hipMemsetAsync(ls2, 0, R*4, stream);
        hipMemsetAsync(obuf, 0, (size_t)R*RH*4, stream);
        k_segmax   <<<CDIV(LGE,256),256,0,stream>>>(val, iiE, lmi, LGE);
        k_segmax   <<<CDIV(LGE,256),256,0,stream>>>(val, jjE, lmj, LGE);
        k_segsumexp<<<CDIV(LGE,256),256,0,stream>>>(val, iiE, lmi, lsi, LGE);
        k_segsumexp<<<CDIV(LGE,256),256,0,stream>>>(val, jjE, lmj, lsj, LGE);
        k_lgat_vsum<<<CDIV(LGE,256),256,0,stream>>>(val, jjE, iiE, lmi, lsi, lmj, lsj, vsum, LGE);
        k_segmax   <<<CDIV(LGE,256),256,0,stream>>>(vsum, jjE, lm2, LGE);
        k_segsumexp<<<CDIV(LGE,256),256,0,stream>>>(vsum, jjE, lm2, ls2, LGE);
        k_edge_agg <<<(int)CDIV((long)LGE*64,256),256,0,stream>>>(vsum, lm2, ls2, jjE, iiE, jjE,
                                                                  xrel, RH, obuf, RH, LGE, RH);
        k_relu2d   <<<CDIV((long)R*RH,256),256,0,stream>>>(obuf, R, RH, RH);
    };
    lgat(remb1, jM, iM, mval, mrg);
    lgat(remb2, jT, iT, tval, tri);

    // ===== x_r = highway(mrg, tri, hrw, hrb) =====
    dim3 gridR(CDIV(RH,GBN), CDIV(R,GBM));
    k_gemm<<<gridR,256,0,stream>>>(mrg, RH, hrw, RH, xrg, RH, R, RH, RH);
    k_highway<<<CDIV((long)R*RH,256),256,0,stream>>>(mrg, RH, xrg, RH, tri, RH, hrb, xr, RH, R, RH, 0);

    // relscore[r] = rel_cat[r]·gat_ar  (rel_emb row k == rel_cat[k % R])
    k_relscore<<<CDIV((long)R*64,256),256,0,stream>>>(mrg, tri, gat_ar, rsc, R, RH);

    // ===== GAT over edge_index_all -> out cols 300..599 (fused softmax gather) =====
    k_rowdot2<<<CDIV((long)N*64,256),256,0,stream>>>(out, OUTC, N, F, gat_ai, gat_aj, sA_, sB_);
    k_edge_score<<<CDIV(EA,256),256,0,stream>>>(sA_, iA, sB_, jA, rsc, rel_all, R, ev, EA);
    k_gather_soft<5><<<gatherGrid,256,0,stream>>>(out, OUTC, ev, jA, rowptrA, cntA, permA,
                                                  out+300, OUTC, N, F, 1);

    // ===== gat_r_to_e over edge_index -> out cols 600..799 =====
    k_rowdot2<<<CDIV((long)N*64,256),256,0,stream>>>(out, OUTC, N, 2*F, g2e_ah, g2e_at, sA_, sB_);
    k_rowdot2<<<CDIV((long)R*64,256),256,0,stream>>>(xr, RH, R, RH, g2e_ar, (const float*)nullptr,
                                                     srel, (float*)nullptr);
    float* evh = ev;
    float* evt = ev + E;
    k_edge_score<<<CDIV(E,256),256,0,stream>>>(sA_, hE, (const float*)nullptr, (const int*)nullptr,
                                               srel, rel, R, evh, E);
    k_edge_score<<<CDIV(E,256),256,0,stream>>>(sB_, tE, (const float*)nullptr, (const int*)nullptr,
                                               srel, rel, R, evt, E);
    k_gather_soft<2><<<gatherGrid,256,0,stream>>>(xr, RH, evh, rel, rowptrH, cntH, permH,
                                                  out+600, OUTC, N, RH, 0);
    k_gather_soft<2><<<gatherGrid,256,0,stream>>>(xr, RH, evt, rel, rowptrT, cntT, permT,
                                                  out+700, OUTC, N, RH, 0);
}

// Round 3
// 3095.808 us; speedup vs baseline: 4.6125x; 1.1902x over previous
//
#include <hip/hip_runtime.h>

#define WAVE 64
#define CDIV(a,b) (((a)+(b)-1)/(b))

typedef float f32x4 __attribute__((ext_vector_type(4)));
typedef unsigned short u16x8 __attribute__((ext_vector_type(8)));

// ---------- bf16 split helpers ----------
__device__ __forceinline__ unsigned short f2bf(float f) {
    unsigned u = __float_as_uint(f);
    unsigned r = (u + 0x7FFFu + ((u >> 16) & 1u)) >> 16;
    return (unsigned short)r;
}
__device__ __forceinline__ float bf2f(unsigned short h) {
    return __uint_as_float(((unsigned)h) << 16);
}

#define MFMA_BF16(acc, a, b) \
    asm volatile("v_mfma_f32_16x16x32_bf16 %0, %1, %2, %0" : "+v"(acc) : "v"(a), "v"(b))

// ---------- monotonic float<->uint encoding for atomicMax on floats ----------
__device__ __forceinline__ unsigned f2mono(float f) {
    unsigned u = __float_as_uint(f);
    return (u & 0x80000000u) ? ~u : (u | 0x80000000u);
}
__device__ __forceinline__ float mono2f(unsigned u) {
    return (u & 0x80000000u) ? __uint_as_float(u & 0x7fffffffu) : __uint_as_float(~u);
}

// =========================================================================
// MFMA GEMM (bf16x3 split, ~fp32 accuracy): C[M,N] = A[M,K] * B[N,K]^T
// =========================================================================
#define TBM 128
#define TBN 64
#define TBK 32
#define LSTR 40   // LDS row stride in shorts (80B: 16B-aligned, <=2-way bank alias)

__global__ __launch_bounds__(256)
void k_gemm_mfma(const float* __restrict__ A, long lda,
                 const float* __restrict__ B, long ldb,
                 float* __restrict__ C, long ldc,
                 int M, int N, int K)
{
    __shared__ unsigned short Ah[TBM][LSTR], Al[TBM][LSTR];
    __shared__ unsigned short Bh[TBN][LSTR], Bl[TBN][LSTR];

    const int tid  = threadIdx.x;
    const int lane = tid & 63;
    const int wid  = tid >> 6;          // 0..3
    const int wr   = wid >> 1;          // wave row 0..1 (64 rows each)
    const int wc   = wid & 1;           // wave col 0..1 (32 cols each)
    const int row0 = blockIdx.y * TBM, col0 = blockIdx.x * TBN;

    f32x4 acc[4][2];
    #pragma unroll
    for (int i = 0; i < 4; ++i)
        #pragma unroll
        for (int j = 0; j < 2; ++j) acc[i][j] = (f32x4){0.f,0.f,0.f,0.f};

    const int arow  = tid >> 1;          // 0..127
    const int acol0 = (tid & 1) * 16;    // 0 / 16
    const int brow  = tid >> 2;          // 0..63
    const int bcol0 = (tid & 3) * 8;     // 0/8/16/24

    const int frow = lane & 15;
    const int koff = (lane >> 4) * 8;

    for (int kt = 0; kt < K; kt += TBK) {
        // ---- stage A tile (128x32), split hi/lo ----
        {
            int gr = row0 + arow;
            const float* src = A + (long)gr * lda + kt + acol0;
            u16x8 hh[2], ll[2];
            #pragma unroll
            for (int c = 0; c < 16; ++c) {
                int gk = kt + acol0 + c;
                float v = (gr < M && gk < K) ? src[c] : 0.0f;
                unsigned short hv = f2bf(v);
                float rv = v - bf2f(hv);
                hh[c >> 3][c & 7] = hv;
                ll[c >> 3][c & 7] = f2bf(rv);
            }
            *(u16x8*)&Ah[arow][acol0]     = hh[0];
            *(u16x8*)&Ah[arow][acol0 + 8] = hh[1];
            *(u16x8*)&Al[arow][acol0]     = ll[0];
            *(u16x8*)&Al[arow][acol0 + 8] = ll[1];
        }
        // ---- stage B tile (64x32), split hi/lo ----
        {
            int gc = col0 + brow;
            const float* src = B + (long)gc * ldb + kt + bcol0;
            u16x8 hh, ll;
            #pragma unroll
            for (int c = 0; c < 8; ++c) {
                int gk = kt + bcol0 + c;
                float v = (gc < N && gk < K) ? src[c] : 0.0f;
                unsigned short hv = f2bf(v);
                float rv = v - bf2f(hv);
                hh[c] = hv;
                ll[c] = f2bf(rv);
            }
            *(u16x8*)&Bh[brow][bcol0] = hh;
            *(u16x8*)&Bl[brow][bcol0] = ll;
        }
        __syncthreads();

        u16x8 afh[4], afl[4], bfh[2], bfl[2];
        #pragma unroll
        for (int mi = 0; mi < 4; ++mi) {
            afh[mi] = *(const u16x8*)&Ah[wr*64 + mi*16 + frow][koff];
            afl[mi] = *(const u16x8*)&Al[wr*64 + mi*16 + frow][koff];
        }
        #pragma unroll
        for (int ni = 0; ni < 2; ++ni) {
            bfh[ni] = *(const u16x8*)&Bh[wc*32 + ni*16 + frow][koff];
            bfl[ni] = *(const u16x8*)&Bl[wc*32 + ni*16 + frow][koff];
        }
        #pragma unroll
        for (int mi = 0; mi < 4; ++mi)
            #pragma unroll
            for (int ni = 0; ni < 2; ++ni) {
                MFMA_BF16(acc[mi][ni], afh[mi], bfh[ni]);
                MFMA_BF16(acc[mi][ni], afl[mi], bfh[ni]);
                MFMA_BF16(acc[mi][ni], afh[mi], bfl[ni]);
            }
        __syncthreads();
    }

    // ---- epilogue: C/D layout col=lane&15, row=(lane>>4)*4+reg ----
    #pragma unroll
    for (int mi = 0; mi < 4; ++mi)
        #pragma unroll
        for (int ni = 0; ni < 2; ++ni)
            #pragma unroll
            for (int r = 0; r < 4; ++r) {
                int row = row0 + wr*64 + mi*16 + (lane >> 4)*4 + r;
                int col = col0 + wc*32 + ni*16 + (lane & 15);
                if (row < M && col < N) C[(long)row*ldc + col] = acc[mi][ni][r];
            }
}

// ---------- small f32 GEMM (kept for the tiny R x RH highway gate) ----------
#define GBM 64
#define GBN 64
#define GBK 16
__global__ __launch_bounds__(256)
void k_gemm(const float* __restrict__ A, long lda,
            const float* __restrict__ B, long ldb,
            float* __restrict__ C, long ldc,
            int M, int N, int K)
{
    __shared__ float As[GBK][GBM + 4];
    __shared__ float Bs[GBK][GBN + 4];
    const int tid = threadIdx.x;
    const int tx = tid & 15, ty = tid >> 4;
    const int row0 = blockIdx.y * GBM, col0 = blockIdx.x * GBN;
    float acc[4][4] = {};
    for (int kt = 0; kt < K; kt += GBK) {
        #pragma unroll
        for (int p = 0; p < 4; ++p) {
            int mn = (tid >> 4) + p * 16;
            int k  = tid & 15;
            int gk = kt + k;
            int gr = row0 + mn;
            As[k][mn] = (gr < M && gk < K) ? A[(long)gr * lda + gk] : 0.0f;
            int gc = col0 + mn;
            Bs[k][mn] = (gc < N && gk < K) ? B[(long)gc * ldb + gk] : 0.0f;
        }
        __syncthreads();
        #pragma unroll
        for (int kk = 0; kk < GBK; ++kk) {
            float a0 = As[kk][ty*4+0], a1 = As[kk][ty*4+1];
            float a2 = As[kk][ty*4+2], a3 = As[kk][ty*4+3];
            float b0 = Bs[kk][tx*4+0], b1 = Bs[kk][tx*4+1];
            float b2 = Bs[kk][tx*4+2], b3 = Bs[kk][tx*4+3];
            acc[0][0] += a0*b0; acc[0][1] += a0*b1; acc[0][2] += a0*b2; acc[0][3] += a0*b3;
            acc[1][0] += a1*b0; acc[1][1] += a1*b1; acc[1][2] += a1*b2; acc[1][3] += a1*b3;
            acc[2][0] += a2*b0; acc[2][1] += a2*b1; acc[2][2] += a2*b2; acc[2][3] += a2*b3;
            acc[3][0] += a3*b0; acc[3][1] += a3*b1; acc[3][2] += a3*b2; acc[3][3] += a3*b3;
        }
        __syncthreads();
    }
    #pragma unroll
    for (int i2 = 0; i2 < 4; ++i2)
        #pragma unroll
        for (int j2 = 0; j2 < 4; ++j2) {
            int r = row0 + ty*4 + i2, c = col0 + tx*4 + j2;
            if (r < M && c < N) C[(long)r*ldc + c] = acc[i2][j2];
        }
}

// ================= CSR build: histogram -> scan -> fill =================
__global__ void k_hist(const int* __restrict__ key, int* __restrict__ cnt, int E) {
    int e = blockIdx.x*blockDim.x + threadIdx.x;
    if (e < E) atomicAdd(&cnt[key[e]], 1);
}
__global__ void k_scan1(const int* __restrict__ in, int* __restrict__ out,
                        int* __restrict__ bsum, int n) {
    __shared__ int sh[256];
    int gid = blockIdx.x*256 + threadIdx.x;
    int v = (gid < n) ? in[gid] : 0;
    sh[threadIdx.x] = v; __syncthreads();
    for (int o = 1; o < 256; o <<= 1) {
        int t = (threadIdx.x >= o) ? sh[threadIdx.x - o] : 0;
        __syncthreads();
        sh[threadIdx.x] += t;
        __syncthreads();
    }
    if (gid < n) out[gid] = sh[threadIdx.x] - v;      // exclusive
    if (threadIdx.x == 255) bsum[blockIdx.x] = sh[255];
}
__global__ void k_scan2(int* __restrict__ bsum, int nb) {   // single block, nb <= 1024
    __shared__ int sh[1024];
    int v = (threadIdx.x < nb) ? bsum[threadIdx.x] : 0;
    sh[threadIdx.x] = v; __syncthreads();
    for (int o = 1; o < 1024; o <<= 1) {
        int t = (threadIdx.x >= o) ? sh[threadIdx.x - o] : 0;
        __syncthreads();
        sh[threadIdx.x] += t;
        __syncthreads();
    }
    if (threadIdx.x < nb) bsum[threadIdx.x] = sh[threadIdx.x] - v;  // exclusive
}
__global__ void k_scan3(int* __restrict__ out, const int* __restrict__ bsum, int n) {
    int gid = blockIdx.x*256 + threadIdx.x;
    if (gid < n) out[gid] += bsum[blockIdx.x];
}
__global__ void k_fill(const int* __restrict__ key, const int* __restrict__ rowptr,
                       int* __restrict__ cursor, int* __restrict__ perm, int E) {
    int e = blockIdx.x*blockDim.x + threadIdx.x;
    if (e >= E) return;
    int k = key[e];
    int p = rowptr[k] + atomicAdd(&cursor[k], 1);
    perm[p] = e;
}

__global__ void k_dinv_cnt(const int* __restrict__ cnt, float* __restrict__ dinv, int n) {
    int i = blockIdx.x*blockDim.x + threadIdx.x;
    if (i < n) { int c = cnt[i]; dinv[i] = (c > 0) ? rsqrtf((float)c) : 0.0f; }
}

// ---------- CSR-order pre-permutation ----------
__global__ void k_prep_gcn(const int* __restrict__ perm, const int* __restrict__ jA,
                           const int* __restrict__ iA, const float* __restrict__ dinv,
                           int* __restrict__ jp, float* __restrict__ nm, int E) {
    int p = blockIdx.x*blockDim.x + threadIdx.x;
    if (p >= E) return;
    int e = perm[p];
    int j = jA[e];
    jp[p] = j;
    nm[p] = dinv[iA[e]] * dinv[j];
}
__global__ void k_permute_f32(const float* __restrict__ src, const int* __restrict__ perm,
                              float* __restrict__ dst, int E) {
    int p = blockIdx.x*blockDim.x + threadIdx.x;
    if (p < E) dst[p] = src[perm[p]];
}
__global__ void k_permute_i32(const int* __restrict__ src, const int* __restrict__ perm,
                              int* __restrict__ dst, int E) {
    int p = blockIdx.x*blockDim.x + threadIdx.x;
    if (p < E) dst[p] = src[perm[p]];
}

// ============ gather aggregations (wave per destination node) ============
// GCN: out[w,:] = sum nm[p] * x[jp[p],:]   (2x unrolled for MLP)
template<int NC>
__global__ void k_gather_norm2(const float* __restrict__ x, long ldx,
                               const int* __restrict__ jp, const float* __restrict__ nm,
                               const int* __restrict__ rowptr, const int* __restrict__ cnt,
                               float* __restrict__ out, long ldo, int n, int F)
{
    int w = (blockIdx.x*blockDim.x + threadIdx.x) >> 6;
    int lane = threadIdx.x & 63;
    if (w >= n) return;
    int beg = rowptr[w], end = beg + cnt[w];
    float acc[NC] = {};
    int e = beg;
    for (; e + 2 <= end; e += 2) {
        int j0 = jp[e], j1 = jp[e+1];
        float w0 = nm[e], w1 = nm[e+1];
        const float* r0 = x + (long)j0*ldx;
        const float* r1 = x + (long)j1*ldx;
        #pragma unroll
        for (int q = 0; q < NC; ++q) { int f = lane + q*64; if (f < F) acc[q] += w0*r0[f] + w1*r1[f]; }
    }
    if (e < end) {
        int j0 = jp[e]; float w0 = nm[e];
        const float* r0 = x + (long)j0*ldx;
        #pragma unroll
        for (int q = 0; q < NC; ++q) { int f = lane + q*64; if (f < F) acc[q] += w0*r0[f]; }
    }
    float* dst = out + (long)w*ldo;
    #pragma unroll
    for (int q = 0; q < NC; ++q) { int f = lane + q*64; if (f < F) dst[f] = acc[q]; }
}

// GAT: fused lane-parallel segment softmax (ev pre-permuted) + 2x-unrolled gather + relu
template<int NC>
__global__ void k_gather_soft2(const float* __restrict__ x, long ldx,
                               const float* __restrict__ evp, const int* __restrict__ jp,
                               const int* __restrict__ rowptr, const int* __restrict__ cnt,
                               float* __restrict__ out, long ldo, int n, int F)
{
    int w = (blockIdx.x*blockDim.x + threadIdx.x) >> 6;
    int lane = threadIdx.x & 63;
    if (w >= n) return;
    int beg = rowptr[w], c = cnt[w];
    float acc[NC] = {};
    if (c > 0) {
        float mx = -3.4e38f;
        for (int t = lane; t < c; t += 64) mx = fmaxf(mx, evp[beg + t]);
        #pragma unroll
        for (int o = 32; o > 0; o >>= 1) mx = fmaxf(mx, __shfl_xor(mx, o));
        float ss = 0.0f;
        for (int t = lane; t < c; t += 64) ss += expf(evp[beg + t] - mx);
        #pragma unroll
        for (int o = 32; o > 0; o >>= 1) ss += __shfl_xor(ss, o);
        float inv = 1.0f / (ss + 1e-16f);
        int e = beg, end = beg + c;
        for (; e + 2 <= end; e += 2) {
            float a0 = expf(evp[e]   - mx) * inv;
            float a1 = expf(evp[e+1] - mx) * inv;
            const float* r0 = x + (long)jp[e]*ldx;
            const float* r1 = x + (long)jp[e+1]*ldx;
            #pragma unroll
            for (int q = 0; q < NC; ++q) { int f = lane + q*64; if (f < F) acc[q] += a0*r0[f] + a1*r1[f]; }
        }
        if (e < end) {
            float a0 = expf(evp[e] - mx) * inv;
            const float* r0 = x + (long)jp[e]*ldx;
            #pragma unroll
            for (int q = 0; q < NC; ++q) { int f = lane + q*64; if (f < F) acc[q] += a0*r0[f]; }
        }
    }
    float* dst = out + (long)w*ldo;
    #pragma unroll
    for (int q = 0; q < NC; ++q) { int f = lane + q*64; if (f < F) dst[f] = fmaxf(acc[q], 0.0f); }
}

// r2e: score computed inline = leaky(snode[w] + srel[relp[p]]); gathers xr rows
template<int NC>
__global__ void k_gather_soft_rel(const float* __restrict__ xr, long ldx,
                                  const float* __restrict__ snode,
                                  const float* __restrict__ srel,
                                  const int* __restrict__ relp,
                                  const int* __restrict__ rowptr, const int* __restrict__ cnt,
                                  float* __restrict__ out, long ldo, int n, int F)
{
    int w = (blockIdx.x*blockDim.x + threadIdx.x) >> 6;
    int lane = threadIdx.x & 63;
    if (w >= n) return;
    int beg = rowptr[w], c = cnt[w];
    float acc[NC] = {};
    if (c > 0) {
        float base = snode[w];
        float mx = -3.4e38f;
        for (int t = lane; t < c; t += 64) {
            float v = base + srel[relp[beg + t]];
            v = (v > 0.0f) ? v : 0.01f*v;
            mx = fmaxf(mx, v);
        }
        #pragma unroll
        for (int o = 32; o > 0; o >>= 1) mx = fmaxf(mx, __shfl_xor(mx, o));
        float ss = 0.0f;
        for (int t = lane; t < c; t += 64) {
            float v = base + srel[relp[beg + t]];
            v = (v > 0.0f) ? v : 0.01f*v;
            ss += expf(v - mx);
        }
        #pragma unroll
        for (int o = 32; o > 0; o >>= 1) ss += __shfl_xor(ss, o);
        float inv = 1.0f / (ss + 1e-16f);
        int e = beg, end = beg + c;
        for (; e + 2 <= end; e += 2) {
            int r0i = relp[e], r1i = relp[e+1];
            float v0 = base + srel[r0i]; v0 = (v0 > 0.0f) ? v0 : 0.01f*v0;
            float v1 = base + srel[r1i]; v1 = (v1 > 0.0f) ? v1 : 0.01f*v1;
            float a0 = expf(v0 - mx) * inv, a1 = expf(v1 - mx) * inv;
            const float* r0 = xr + (long)r0i*ldx;
            const float* r1 = xr + (long)r1i*ldx;
            #pragma unroll
            for (int q = 0; q < NC; ++q) { int f = lane + q*64; if (f < F) acc[q] += a0*r0[f] + a1*r1[f]; }
        }
        if (e < end) {
            int r0i = relp[e];
            float v0 = base + srel[r0i]; v0 = (v0 > 0.0f) ? v0 : 0.01f*v0;
            float a0 = expf(v0 - mx) * inv;
            const float* r0 = xr + (long)r0i*ldx;
            #pragma unroll
            for (int q = 0; q < NC; ++q) { int f = lane + q*64; if (f < F) acc[q] += a0*r0[f]; }
        }
    }
    float* dst = out + (long)w*ldo;
    #pragma unroll
    for (int q = 0; q < NC; ++q) { int f = lane + q*64; if (f < F) dst[f] = acc[q]; }
}

// ---------- highway combine: out = sig(gl + b)*x2' + (1-sig)*x1 ----------
__global__ void k_highway(const float* __restrict__ x1, long ld1,
                          const float* __restrict__ gl, long ldg,
                          const float* __restrict__ x2, long ld2,
                          const float* __restrict__ bias,
                          float* __restrict__ out, long ldo,
                          long rows, int F, int relu_x2)
{
    long idx = (long)blockIdx.x*blockDim.x + threadIdx.x;
    if (idx >= rows * (long)F) return;
    long r = idx / F; int c = (int)(idx % F);
    float g = 1.0f / (1.0f + expf(-(gl[r*ldg+c] + bias[c])));
    float v2 = x2[r*ld2+c]; if (relu_x2) v2 = fmaxf(v2, 0.0f);
    float v1 = x1[r*ld1+c];
    out[r*ldo+c] = g*v2 + (1.0f-g)*v1;
}

// ---------- segment softmax building blocks (small l_gat path only) ----------
__global__ void k_segmax(const float* __restrict__ ev, const int* __restrict__ idx,
                         unsigned* __restrict__ m, int E) {
    int e = blockIdx.x*blockDim.x + threadIdx.x;
    if (e < E) atomicMax(&m[idx[e]], f2mono(ev[e]));
}
__global__ void k_segsumexp(const float* __restrict__ ev, const int* __restrict__ idx,
                            const unsigned* __restrict__ m, float* __restrict__ s, int E) {
    int e = blockIdx.x*blockDim.x + threadIdx.x;
    if (e < E) atomicAdd(&s[idx[e]], expf(ev[e] - mono2f(m[idx[e]])));
}

// ---------- GAT edge score: ev = leaky( sa[ia] + sb[ib] + sc[ic % cmod] ) ----------
__global__ void k_edge_score(const float* __restrict__ sa, const int* __restrict__ ia,
                             const float* __restrict__ sb, const int* __restrict__ ib,
                             const float* __restrict__ sc, const int* __restrict__ ic, int cmod,
                             float* __restrict__ ev, int E)
{
    int e = blockIdx.x*blockDim.x + threadIdx.x;
    if (e >= E) return;
    float v = sa[ia[e]] + sb[ib[e]] + sc[ic[e] % cmod];
    ev[e] = (v > 0.0f) ? v : 0.01f*v;
}

// ---------- l_gat vsum ----------
__global__ void k_lgat_vsum(const float* __restrict__ val,
                            const int* __restrict__ jj, const int* __restrict__ ii,
                            const unsigned* __restrict__ mi, const float* __restrict__ si,
                            const unsigned* __restrict__ mj, const float* __restrict__ sj,
                            float* __restrict__ vsum, int E)
{
    int e = blockIdx.x*blockDim.x + threadIdx.x;
    if (e >= E) return;
    float v = val[e];
    int i = ii[e], j = jj[e];
    float pi = expf(v - mono2f(mi[i])) / (si[i] + 1e-16f);
    float pj = expf(v - mono2f(mj[j])) / (sj[j] + 1e-16f);
    vsum[e] = pi + pj;
}

// ---------- atomic softmax-weighted scatter (l_gat only; key_a != key_out) ----------
__global__ void k_edge_agg(const float* __restrict__ ev,
                           const unsigned* __restrict__ m, const float* __restrict__ s,
                           const int* __restrict__ ka, const int* __restrict__ ko,
                           const int* __restrict__ ks,
                           const float* __restrict__ x, long ldx,
                           float* __restrict__ out, long ldo,
                           int E, int F)
{
    int w = (blockIdx.x*blockDim.x + threadIdx.x) >> 6;
    int lane = threadIdx.x & 63;
    if (w >= E) return;
    int a = ka[w];
    float alpha = expf(ev[w] - mono2f(m[a])) / (s[a] + 1e-16f);
    const float4* src = (const float4*)(x + (long)ks[w]*ldx);
    float* dst = out + (long)ko[w]*ldo;
    int nf4 = F >> 2;
    for (int f = lane; f < nf4; f += WAVE) {
        float4 v = src[f];
        atomicAdd(&dst[f*4+0], alpha*v.x);
        atomicAdd(&dst[f*4+1], alpha*v.y);
        atomicAdd(&dst[f*4+2], alpha*v.z);
        atomicAdd(&dst[f*4+3], alpha*v.w);
    }
}

__global__ void k_relu2d(float* __restrict__ p, long rows, int cols, long ld) {
    long idx = (long)blockIdx.x*blockDim.x + threadIdx.x;
    if (idx >= rows*(long)cols) return;
    long r = idx / cols; int c = (int)(idx % cols);
    float v = p[r*ld+c];
    p[r*ld+c] = fmaxf(v, 0.0f);
}

// ---------- row dots: oa[r] = x[r]·a, ob[r] = x[r]·b  (wave per row) ----------
__global__ void k_rowdot2(const float* __restrict__ x, long ldx, int rows, int K,
                          const float* __restrict__ a, const float* __restrict__ b,
                          float* __restrict__ oa, float* __restrict__ ob)
{
    int w = (blockIdx.x*blockDim.x + threadIdx.x) >> 6;
    int lane = threadIdx.x & 63;
    if (w >= rows) return;
    const float* xr = x + (long)w*ldx;
    float sa = 0.0f, sb = 0.0f;
    for (int k = lane; k < K; k += WAVE) {
        float v = xr[k];
        sa += v * a[k];
        if (b) sb += v * b[k];
    }
    #pragma unroll
    for (int off = 32; off > 0; off >>= 1) {
        sa += __shfl_down(sa, off);
        if (b) sb += __shfl_down(sb, off);
    }
    if (lane == 0) { oa[w] = sa; if (ob) ob[w] = sb; }
}

// ---------- relscore[r] = merge[r]·ar[0:RH] + tri[r]·ar[RH:2RH] ----------
__global__ void k_relscore(const float* __restrict__ mg, const float* __restrict__ tr,
                           const float* __restrict__ ar, float* __restrict__ out, int R, int RH)
{
    int w = (blockIdx.x*blockDim.x + threadIdx.x) >> 6;
    int lane = threadIdx.x & 63;
    if (w >= R) return;
    float s = 0.0f;
    for (int k = lane; k < RH; k += WAVE)
        s += mg[(long)w*RH+k]*ar[k] + tr[(long)w*RH+k]*ar[RH+k];
    #pragma unroll
    for (int off = 32; off > 0; off >>= 1) s += __shfl_down(s, off);
    if (lane == 0) out[w] = s;
}

extern "C" void kernel_launch(void* const* d_in, const int* in_sizes, int n_in,
                              void* d_out, int out_size, void* d_ws, size_t ws_size,
                              hipStream_t stream)
{
    const float* x_e   = (const float*)d_in[0];
    const float* mval  = (const float*)d_in[1];
    const float* tval  = (const float*)d_in[2];
    const float* g1w   = (const float*)d_in[3];
    const float* h1w   = (const float*)d_in[4];
    const float* h1b   = (const float*)d_in[5];
    const float* g2w   = (const float*)d_in[6];
    const float* h2w   = (const float*)d_in[7];
    const float* h2b   = (const float*)d_in[8];
    const float* remb1 = (const float*)d_in[9];
    const float* remb2 = (const float*)d_in[10];
    const float* hrw   = (const float*)d_in[11];
    const float* hrb   = (const float*)d_in[12];
    const float* gat_ai= (const float*)d_in[13];
    const float* gat_aj= (const float*)d_in[14];
    const float* gat_ar= (const float*)d_in[15];
    const float* g2e_ah= (const float*)d_in[16];
    const float* g2e_at= (const float*)d_in[17];
    const float* g2e_ar= (const float*)d_in[18];
    const int* edge_index     = (const int*)d_in[19];
    const int* rel            = (const int*)d_in[20];
    const int* edge_index_all = (const int*)d_in[21];
    const int* rel_all        = (const int*)d_in[22];
    const int* lg_merge       = (const int*)d_in[23];
    const int* lg_tri         = (const int*)d_in[24];

    const int F    = 300;
    const int RH   = 100;
    const int N    = in_sizes[0] / F;      // 100000
    const int E    = in_sizes[20];         // 400000
    const int EA   = in_sizes[22];         // 800000
    const int LGE  = in_sizes[1];          // 60000
    const int R    = in_sizes[9] / RH;     // 2000
    const long OUTC = 800;

    const int* jA = edge_index_all;        // ei[0] = j (source)
    const int* iA = edge_index_all + EA;   // ei[1] = i (dest)
    const int* hE = edge_index;            // ei[0] = h
    const int* tE = edge_index + E;        // ei[1] = t
    const int* jM = lg_merge;  const int* iM = lg_merge + LGE;
    const int* jT = lg_tri;    const int* iT = lg_tri  + LGE;

    float* ws = (float*)d_ws;
    size_t off = 0;
    auto alloc = [&](size_t n) { float* p = ws + off; off += n; return p; };
    float*    A    = alloc((size_t)N*F);     // GEMM scratch [N,300]
    float*    dinv = alloc(N);
    float*    ev   = alloc(EA);
    float*    evp  = alloc(EA);
    float*    sA_  = alloc(N);
    float*    sB_  = alloc(N);
    float*    mrg  = alloc((size_t)R*RH);
    float*    tri  = alloc((size_t)R*RH);
    float*    xr   = alloc((size_t)R*RH);
    float*    xrg  = alloc((size_t)R*RH);
    unsigned* lmi  = (unsigned*)alloc(R);  float* lsi = alloc(R);
    unsigned* lmj  = (unsigned*)alloc(R);  float* lsj = alloc(R);
    unsigned* lm2  = (unsigned*)alloc(R);  float* ls2 = alloc(R);
    float*    vsum = alloc(LGE);
    float*    rsc  = alloc(R);
    float*    srel = alloc(R);
    // CSR structures + permuted per-slot data
    int*   bsum    = (int*)alloc(1024);
    int*   cursor  = (int*)alloc(N);
    int*   rowptrA = (int*)alloc(N); int* cntA = (int*)alloc(N); int* permA = (int*)alloc(EA);
    int*   rowptrH = (int*)alloc(N); int* cntH = (int*)alloc(N); int* permH = (int*)alloc(E);
    int*   rowptrT = (int*)alloc(N); int* cntT = (int*)alloc(N); int* permT = (int*)alloc(E);
    int*   jpA     = (int*)alloc(EA);
    float* nmA     = alloc(EA);
    int*   relpH   = (int*)alloc(E);
    int*   relpT   = (int*)alloc(E);

    float* out = (float*)d_out;              // [N, 800]

    const long NF = (long)N * F;
    const int  nb = CDIV(N, 256);            // 391 <= 1024
    dim3 mfmaGrid(CDIV(F, TBN), CDIV(N, TBM));     // (5, 782)
    const int gatherGrid = CDIV(N, 4);       // wave per node, 4 waves/block

    auto build_csr = [&](const int* key, int E_, int* rowptr, int* cnt, int* perm) {
        hipMemsetAsync(cnt, 0, (size_t)N*4, stream);
        k_hist<<<CDIV(E_,256),256,0,stream>>>(key, cnt, E_);
        k_scan1<<<nb,256,0,stream>>>(cnt, rowptr, bsum, N);
        k_scan2<<<1,1024,0,stream>>>(bsum, nb);
        k_scan3<<<nb,256,0,stream>>>(rowptr, bsum, N);
        hipMemsetAsync(cursor, 0, (size_t)N*4, stream);
        k_fill<<<CDIV(E_,256),256,0,stream>>>(key, rowptr, cursor, perm, E_);
    };

    // ===== CSRs (dest-keyed for GCN/GAT; h/t-keyed for r2e) + pre-permutes =====
    build_csr(iA, EA, rowptrA, cntA, permA);
    build_csr(hE, E,  rowptrH, cntH, permH);
    build_csr(tE, E,  rowptrT, cntT, permT);
    k_dinv_cnt<<<CDIV(N,256),256,0,stream>>>(cntA, dinv, N);
    k_prep_gcn<<<CDIV(EA,256),256,0,stream>>>(permA, jA, iA, dinv, jpA, nmA, EA);
    k_permute_i32<<<CDIV(E,256),256,0,stream>>>(rel, permH, relpH, E);
    k_permute_i32<<<CDIV(E,256),256,0,stream>>>(rel, permT, relpT, E);

    // ===== GCN layer 1 + highway (agg scratch = out cols 300..599) =====
    k_gemm_mfma<<<mfmaGrid,256,0,stream>>>(x_e, F, g1w, F, A, F, N, F, F);
    k_gather_norm2<5><<<gatherGrid,256,0,stream>>>(A, F, jpA, nmA, rowptrA, cntA,
                                                   out+300, OUTC, N, F);
    k_gemm_mfma<<<mfmaGrid,256,0,stream>>>(x_e, F, h1w, F, A, F, N, F, F);
    k_highway<<<CDIV(NF,256),256,0,stream>>>(x_e, F, A, F, out+300, OUTC, h1b, out, OUTC, N, F, 1);

    // ===== GCN layer 2 + highway (h1 lives in out cols 0..299) =====
    k_gemm_mfma<<<mfmaGrid,256,0,stream>>>(out, OUTC, g2w, F, A, F, N, F, F);
    k_gather_norm2<5><<<gatherGrid,256,0,stream>>>(A, F, jpA, nmA, rowptrA, cntA,
                                                   out+300, OUTC, N, F);
    k_gemm_mfma<<<mfmaGrid,256,0,stream>>>(out, OUTC, h2w, F, A, F, N, F, F);
    k_highway<<<CDIV(NF,256),256,0,stream>>>(out, OUTC, A, F, out+300, OUTC, h2b, out, OUTC, N, F, 1);

    // ===== l_gat on the two line graphs (small; atomic path) =====
    auto lgat = [&](const float* xrel, const int* jjE, const int* iiE, const float* val, float* obuf) {
        hipMemsetAsync(lmi, 0, R*4, stream); hipMemsetAsync(lsi, 0, R*4, stream);
        hipMemsetAsync(lmj, 0, R*4, stream); hipMemsetAsync(lsj, 0, R*4, stream);
        hipMemsetAsync(lm2, 0, R*4, stream); hipMemsetAsync(ls2, 0, R*4, stream);
        hipMemsetAsync(obuf, 0, (size_t)R*RH*4, stream);
        k_segmax   <<<CDIV(LGE,256),256,0,stream>>>(val, iiE, lmi, LGE);
        k_segmax   <<<CDIV(LGE,256),256,0,stream>>>(val, jjE, lmj, LGE);
        k_segsumexp<<<CDIV(LGE,256),256,0,stream>>>(val, iiE, lmi, lsi, LGE);
        k_segsumexp<<<CDIV(LGE,256),256,0,stream>>>(val, jjE, lmj, lsj, LGE);
        k_lgat_vsum<<<CDIV(LGE,256),256,0,stream>>>(val, jjE, iiE, lmi, lsi, lmj, lsj, vsum, LGE);
        k_segmax   <<<CDIV(LGE,256),256,0,stream>>>(vsum, jjE, lm2, LGE);
        k_segsumexp<<<CDIV(LGE,256),256,0,stream>>>(vsum, jjE, lm2, ls2, LGE);
        k_edge_agg <<<(int)CDIV((long)LGE*64,256),256,0,stream>>>(vsum, lm2, ls2, jjE, iiE, jjE,
                                                                  xrel, RH, obuf, RH, LGE, RH);
        k_relu2d   <<<CDIV((long)R*RH,256),256,0,stream>>>(obuf, R, RH, RH);
    };
    lgat(remb1, jM, iM, mval, mrg);
    lgat(remb2, jT, iT, tval, tri);

    // ===== x_r = highway(mrg, tri, hrw, hrb) =====
    dim3 gridR(CDIV(RH,GBN), CDIV(R,GBM));
    k_gemm<<<gridR,256,0,stream>>>(mrg, RH, hrw, RH, xrg, RH, R, RH, RH);
    k_highway<<<CDIV((long)R*RH,256),256,0,stream>>>(mrg, RH, xrg, RH, tri, RH, hrb, xr, RH, R, RH, 0);

    // relscore[r] = rel_cat[r]·gat_ar  (rel_emb row k == rel_cat[k % R])
    k_relscore<<<CDIV((long)R*64,256),256,0,stream>>>(mrg, tri, gat_ar, rsc, R, RH);

    // ===== GAT over edge_index_all -> out cols 300..599 (fused softmax gather) =====
    k_rowdot2<<<CDIV((long)N*64,256),256,0,stream>>>(out, OUTC, N, F, gat_ai, gat_aj, sA_, sB_);
    k_edge_score<<<CDIV(EA,256),256,0,stream>>>(sA_, iA, sB_, jA, rsc, rel_all, R, ev, EA);
    k_permute_f32<<<CDIV(EA,256),256,0,stream>>>(ev, permA, evp, EA);
    k_gather_soft2<5><<<gatherGrid,256,0,stream>>>(out, OUTC, evp, jpA, rowptrA, cntA,
                                                   out+300, OUTC, N, F);

    // ===== gat_r_to_e over edge_index -> out cols 600..799 (inline scores) =====
    k_rowdot2<<<CDIV((long)N*64,256),256,0,stream>>>(out, OUTC, N, 2*F, g2e_ah, g2e_at, sA_, sB_);
    k_rowdot2<<<CDIV((long)R*64,256),256,0,stream>>>(xr, RH, R, RH, g2e_ar, (const float*)nullptr,
                                                     srel, (float*)nullptr);
    k_gather_soft_rel<2><<<gatherGrid,256,0,stream>>>(xr, RH, sA_, srel, relpH, rowptrH, cntH,
                                                      out+600, OUTC, N, RH);
    k_gather_soft_rel<2><<<gatherGrid,256,0,stream>>>(xr, RH, sB_, srel, relpT, rowptrT, cntT,
                                                      out+700, OUTC, N, RH);
}

// Round 4
// 2363.969 us; speedup vs baseline: 6.0405x; 1.3096x over previous
//
#include <hip/hip_runtime.h>

#define WAVE 64
#define CDIV(a,b) (((a)+(b)-1)/(b))

typedef float f32x16 __attribute__((ext_vector_type(16)));
typedef unsigned short u16x8 __attribute__((ext_vector_type(8)));

// ---------- bf16 helpers: hi = truncate, lo = round(residual) ----------
__device__ __forceinline__ unsigned short f2bf_rne(float f) {
    unsigned u = __float_as_uint(f);
    unsigned r = (u + 0x7FFFu + ((u >> 16) & 1u)) >> 16;
    return (unsigned short)r;
}
__device__ __forceinline__ float bf2f(unsigned short h) {
    return __uint_as_float(((unsigned)h) << 16);
}

#define MFMA32(acc, a, b) \
    asm volatile("v_mfma_f32_32x32x16_bf16 %0, %1, %2, %0" : "+v"(acc) : "v"(a), "v"(b))

// ---------- monotonic float<->uint encoding for atomicMax on floats ----------
__device__ __forceinline__ unsigned f2mono(float f) {
    unsigned u = __float_as_uint(f);
    return (u & 0x80000000u) ? ~u : (u | 0x80000000u);
}
__device__ __forceinline__ float mono2f(unsigned u) {
    return (u & 0x80000000u) ? __uint_as_float(u & 0x7fffffffu) : __uint_as_float(~u);
}
__device__ __forceinline__ float leaky(float v) { return (v > 0.0f) ? v : 0.01f*v; }

// =========================================================================
// k_gemm300: C[M,N] = A[M,K] * B[N,K]^T, N<=320, bf16x3 split (~fp32 acc).
// Full-N blocks (A read once). Fragment-order LDS: lane l reads byte l*16
// of its tile chunk -> conflict-free ds_read_b128. Double-buffered.
// Block: 512 threads = 8 waves = 4 rowgroups x 2 colgroups.
// Wave output: 32 rows x 160 cols (5x 32x32 MFMA tiles).
// =========================================================================
#define KSTEP 16
__global__ __launch_bounds__(512)
void k_gemm300(const float* __restrict__ A, long lda,
               const float* __restrict__ B, long ldb,
               float* __restrict__ C, long ldc,
               int M, int N, int K)
{
    __shared__ __align__(16) unsigned short Ah[2][4][64][8], Al[2][4][64][8];
    __shared__ __align__(16) unsigned short Bh[2][10][64][8], Bl[2][10][64][8];

    const int tid  = threadIdx.x;
    const int lane = tid & 63;
    const int wid  = tid >> 6;
    const int row0 = blockIdx.x * 128;
    const int nk   = CDIV(K, KSTEP);

    // staging roles: threads 0..319 stage B rows, 320..447 stage A rows
    const bool isB = (tid < 320);
    const bool isA = (tid >= 320 && tid < 448);
    const int  srow = isB ? tid : (tid - 320);
    const float* gsrc = isB ? (B + (long)srow * ldb)
                            : (A + (long)(row0 + srow) * lda);
    const bool vrow = isB ? (srow < N) : (isA && (row0 + srow) < M);
    const int  stile = srow >> 5, slot = srow & 31;

    const int wrt = wid >> 1;          // rowtile 0..3
    const int wcg = wid & 1;           // colgroup 0..1 (cols wcg*160 ..)

    f32x16 acc[5];
    #pragma unroll
    for (int c = 0; c < 5; ++c) acc[c] = (f32x16)0.0f;

    // ---- prologue: stage kstep 0 into buf 0 ----
    {
        float v[16];
        #pragma unroll
        for (int i = 0; i < 4; ++i) {
            float4 x4 = {0,0,0,0};
            if ((isA || isB) && vrow && (i*4 + 4) <= K) x4 = *(const float4*)(gsrc + i*4);
            v[i*4+0]=x4.x; v[i*4+1]=x4.y; v[i*4+2]=x4.z; v[i*4+3]=x4.w;
        }
        if (isA || isB) {
            u16x8 h0, h1, l0, l1;
            #pragma unroll
            for (int i = 0; i < 8; ++i) {
                unsigned u0 = __float_as_uint(v[i]);
                unsigned short hh = (unsigned short)(u0 >> 16);
                h0[i] = hh; l0[i] = f2bf_rne(v[i] - bf2f(hh));
                unsigned u1 = __float_as_uint(v[8+i]);
                unsigned short hh1 = (unsigned short)(u1 >> 16);
                h1[i] = hh1; l1[i] = f2bf_rne(v[8+i] - bf2f(hh1));
            }
            unsigned short* dh = isB ? &Bh[0][stile][slot][0] : &Ah[0][stile][slot][0];
            unsigned short* dl = isB ? &Bl[0][stile][slot][0] : &Al[0][stile][slot][0];
            *(u16x8*)dh = h0; *(u16x8*)(dh + 256) = h1;
            *(u16x8*)dl = l0; *(u16x8*)(dl + 256) = l1;
        }
    }
    __syncthreads();

    for (int t = 0; t < nk; ++t) {
        const int cur = t & 1;
        const bool havenext = (t + 1 < nk);
        // (1) issue next-kstep global loads early (latency hides under MFMA)
        float v[16];
        if (havenext && (isA || isB)) {
            int k0 = (t + 1) * KSTEP;
            #pragma unroll
            for (int i = 0; i < 4; ++i) {
                float4 x4 = {0,0,0,0};
                if (vrow && (k0 + i*4 + 4) <= K) x4 = *(const float4*)(gsrc + k0 + i*4);
                v[i*4+0]=x4.x; v[i*4+1]=x4.y; v[i*4+2]=x4.z; v[i*4+3]=x4.w;
            }
        }
        // (2) fragments + MFMA from buf[cur]
        {
            u16x8 afh = *(const u16x8*)&Ah[cur][wrt][lane][0];
            u16x8 afl = *(const u16x8*)&Al[cur][wrt][lane][0];
            #pragma unroll
            for (int c = 0; c < 5; ++c) {
                int bt = wcg*5 + c;
                u16x8 bfh = *(const u16x8*)&Bh[cur][bt][lane][0];
                u16x8 bfl = *(const u16x8*)&Bl[cur][bt][lane][0];
                MFMA32(acc[c], afh, bfh);
                MFMA32(acc[c], afl, bfh);
                MFMA32(acc[c], afh, bfl);
            }
        }
        // (3) convert + ds_write next tile into buf[cur^1]
        if (havenext && (isA || isB)) {
            u16x8 h0, h1, l0, l1;
            #pragma unroll
            for (int i = 0; i < 8; ++i) {
                unsigned u0 = __float_as_uint(v[i]);
                unsigned short hh = (unsigned short)(u0 >> 16);
                h0[i] = hh; l0[i] = f2bf_rne(v[i] - bf2f(hh));
                unsigned u1 = __float_as_uint(v[8+i]);
                unsigned short hh1 = (unsigned short)(u1 >> 16);
                h1[i] = hh1; l1[i] = f2bf_rne(v[8+i] - bf2f(hh1));
            }
            int nb = cur ^ 1;
            unsigned short* dh = isB ? &Bh[nb][stile][slot][0] : &Ah[nb][stile][slot][0];
            unsigned short* dl = isB ? &Bl[nb][stile][slot][0] : &Al[nb][stile][slot][0];
            *(u16x8*)dh = h0; *(u16x8*)(dh + 256) = h1;
            *(u16x8*)dl = l0; *(u16x8*)(dl + 256) = l1;
        }
        __syncthreads();
    }

    // ---- epilogue: C/D layout col=lane&31, row=(reg&3)+8*(reg>>2)+4*(lane>>5) ----
    const int crow0 = row0 + wrt*32 + 4*(lane >> 5);
    const int ccol  = wcg*160 + (lane & 31);
    #pragma unroll
    for (int c = 0; c < 5; ++c) {
        int col = ccol + c*32;
        if (col >= N) continue;
        #pragma unroll
        for (int reg = 0; reg < 16; ++reg) {
            int row = crow0 + (reg & 3) + 8*(reg >> 2);
            if (row < M) C[(long)row*ldc + col] = acc[c][reg];
        }
    }
}

// ---------- small f32 GEMM (tiny R x RH highway gate) ----------
#define GBM 64
#define GBN 64
#define GBK 16
__global__ __launch_bounds__(256)
void k_gemm(const float* __restrict__ A, long lda,
            const float* __restrict__ B, long ldb,
            float* __restrict__ C, long ldc,
            int M, int N, int K)
{
    __shared__ float As[GBK][GBM + 4];
    __shared__ float Bs[GBK][GBN + 4];
    const int tid = threadIdx.x;
    const int tx = tid & 15, ty = tid >> 4;
    const int row0 = blockIdx.y * GBM, col0 = blockIdx.x * GBN;
    float acc[4][4] = {};
    for (int kt = 0; kt < K; kt += GBK) {
        #pragma unroll
        for (int p = 0; p < 4; ++p) {
            int mn = (tid >> 4) + p * 16;
            int k  = tid & 15;
            int gk = kt + k;
            int gr = row0 + mn;
            As[k][mn] = (gr < M && gk < K) ? A[(long)gr * lda + gk] : 0.0f;
            int gc = col0 + mn;
            Bs[k][mn] = (gc < N && gk < K) ? B[(long)gc * ldb + gk] : 0.0f;
        }
        __syncthreads();
        #pragma unroll
        for (int kk = 0; kk < GBK; ++kk) {
            float a0 = As[kk][ty*4+0], a1 = As[kk][ty*4+1];
            float a2 = As[kk][ty*4+2], a3 = As[kk][ty*4+3];
            float b0 = Bs[kk][tx*4+0], b1 = Bs[kk][tx*4+1];
            float b2 = Bs[kk][tx*4+2], b3 = Bs[kk][tx*4+3];
            acc[0][0] += a0*b0; acc[0][1] += a0*b1; acc[0][2] += a0*b2; acc[0][3] += a0*b3;
            acc[1][0] += a1*b0; acc[1][1] += a1*b1; acc[1][2] += a1*b2; acc[1][3] += a1*b3;
            acc[2][0] += a2*b0; acc[2][1] += a2*b1; acc[2][2] += a2*b2; acc[2][3] += a2*b3;
            acc[3][0] += a3*b0; acc[3][1] += a3*b1; acc[3][2] += a3*b2; acc[3][3] += a3*b3;
        }
        __syncthreads();
    }
    #pragma unroll
    for (int i2 = 0; i2 < 4; ++i2)
        #pragma unroll
        for (int j2 = 0; j2 < 4; ++j2) {
            int r = row0 + ty*4 + i2, c = col0 + tx*4 + j2;
            if (r < M && c < N) C[(long)r*ldc + c] = acc[i2][j2];
        }
}

// ================= CSR build: histogram -> scan -> fill =================
__global__ void k_hist(const int* __restrict__ key, int* __restrict__ cnt, int E) {
    int e = blockIdx.x*blockDim.x + threadIdx.x;
    if (e < E) atomicAdd(&cnt[key[e]], 1);
}
__global__ void k_scan1(const int* __restrict__ in, int* __restrict__ out,
                        int* __restrict__ bsum, int n) {
    __shared__ int sh[256];
    int gid = blockIdx.x*256 + threadIdx.x;
    int v = (gid < n) ? in[gid] : 0;
    sh[threadIdx.x] = v; __syncthreads();
    for (int o = 1; o < 256; o <<= 1) {
        int t = (threadIdx.x >= o) ? sh[threadIdx.x - o] : 0;
        __syncthreads();
        sh[threadIdx.x] += t;
        __syncthreads();
    }
    if (gid < n) out[gid] = sh[threadIdx.x] - v;      // exclusive
    if (threadIdx.x == 255) bsum[blockIdx.x] = sh[255];
}
__global__ void k_scan2(int* __restrict__ bsum, int nb) {   // single block, nb <= 1024
    __shared__ int sh[1024];
    int v = (threadIdx.x < nb) ? bsum[threadIdx.x] : 0;
    sh[threadIdx.x] = v; __syncthreads();
    for (int o = 1; o < 1024; o <<= 1) {
        int t = (threadIdx.x >= o) ? sh[threadIdx.x - o] : 0;
        __syncthreads();
        sh[threadIdx.x] += t;
        __syncthreads();
    }
    if (threadIdx.x < nb) bsum[threadIdx.x] = sh[threadIdx.x] - v;  // exclusive
}
__global__ void k_scan3(int* __restrict__ out, const int* __restrict__ bsum, int n) {
    int gid = blockIdx.x*256 + threadIdx.x;
    if (gid < n) out[gid] += bsum[blockIdx.x];
}
__global__ void k_fill(const int* __restrict__ key, const int* __restrict__ rowptr,
                       int* __restrict__ cursor, int* __restrict__ perm, int E) {
    int e = blockIdx.x*blockDim.x + threadIdx.x;
    if (e >= E) return;
    int k = key[e];
    int p = rowptr[k] + atomicAdd(&cursor[k], 1);
    perm[p] = e;
}
__global__ void k_dinv_cnt(const int* __restrict__ cnt, float* __restrict__ dinv, int n) {
    int i = blockIdx.x*blockDim.x + threadIdx.x;
    if (i < n) { int c = cnt[i]; dinv[i] = (c > 0) ? rsqrtf((float)c) : 0.0f; }
}

// ---------- CSR-order pre-permutation ----------
__global__ void k_prep_gcn(const int* __restrict__ perm, const int* __restrict__ jA,
                           const int* __restrict__ iA, const float* __restrict__ dinv,
                           int* __restrict__ jp, float* __restrict__ nm, int E) {
    int p = blockIdx.x*blockDim.x + threadIdx.x;
    if (p >= E) return;
    int e = perm[p];
    int j = jA[e];
    jp[p] = j;
    nm[p] = dinv[iA[e]] * dinv[j];
}
__global__ void k_permute_i32(const int* __restrict__ src, const int* __restrict__ perm,
                              int* __restrict__ dst, int E) {
    int p = blockIdx.x*blockDim.x + threadIdx.x;
    if (p < E) dst[p] = src[perm[p]];
}
__global__ void k_permute_mod(const int* __restrict__ src, const int* __restrict__ perm,
                              int* __restrict__ dst, int E, int mod) {
    int p = blockIdx.x*blockDim.x + threadIdx.x;
    if (p < E) dst[p] = src[perm[p]] % mod;
}

// ============ gather aggregations (wave per destination node, F=300) ============
// GCN: out[w,:] = sum nm[p] * x[jp[p],:]; float2 lanes: i0=lane, i1=64+lane, i2=128+lane(<150)
__global__ void k_gather300(const float* __restrict__ x, long ldx,
                            const int* __restrict__ jp, const float* __restrict__ nm,
                            const int* __restrict__ rowptr, const int* __restrict__ cnt,
                            float* __restrict__ out, long ldo, int n)
{
    int w = (blockIdx.x*blockDim.x + threadIdx.x) >> 6;
    int lane = threadIdx.x & 63;
    if (w >= n) return;
    int beg = rowptr[w], end = beg + cnt[w];
    const int i0 = lane, i1 = lane + 64, i2 = lane + 128;
    const bool t3 = (lane < 22);
    float2 a0 = {0,0}, a1 = {0,0}, a2 = {0,0};
    int e = beg;
    for (; e + 4 <= end; e += 4) {
        const float2* r0 = (const float2*)(x + (long)jp[e]  *ldx);
        const float2* r1 = (const float2*)(x + (long)jp[e+1]*ldx);
        const float2* r2 = (const float2*)(x + (long)jp[e+2]*ldx);
        const float2* r3 = (const float2*)(x + (long)jp[e+3]*ldx);
        float w0 = nm[e], w1 = nm[e+1], w2 = nm[e+2], w3 = nm[e+3];
        float2 v;
        v = r0[i0]; a0.x += w0*v.x; a0.y += w0*v.y;
        v = r1[i0]; a0.x += w1*v.x; a0.y += w1*v.y;
        v = r2[i0]; a0.x += w2*v.x; a0.y += w2*v.y;
        v = r3[i0]; a0.x += w3*v.x; a0.y += w3*v.y;
        v = r0[i1]; a1.x += w0*v.x; a1.y += w0*v.y;
        v = r1[i1]; a1.x += w1*v.x; a1.y += w1*v.y;
        v = r2[i1]; a1.x += w2*v.x; a1.y += w2*v.y;
        v = r3[i1]; a1.x += w3*v.x; a1.y += w3*v.y;
        if (t3) {
            v = r0[i2]; a2.x += w0*v.x; a2.y += w0*v.y;
            v = r1[i2]; a2.x += w1*v.x; a2.y += w1*v.y;
            v = r2[i2]; a2.x += w2*v.x; a2.y += w2*v.y;
            v = r3[i2]; a2.x += w3*v.x; a2.y += w3*v.y;
        }
    }
    for (; e < end; ++e) {
        const float2* r0 = (const float2*)(x + (long)jp[e]*ldx);
        float w0 = nm[e];
        float2 v;
        v = r0[i0]; a0.x += w0*v.x; a0.y += w0*v.y;
        v = r0[i1]; a1.x += w0*v.x; a1.y += w0*v.y;
        if (t3) { v = r0[i2]; a2.x += w0*v.x; a2.y += w0*v.y; }
    }
    float2* dst = (float2*)(out + (long)w*ldo);
    dst[i0] = a0; dst[i1] = a1;
    if (t3) dst[i2] = a2;
}

// GAT: fused edge score + segment softmax + weighted gather + relu (F=300)
__global__ void k_gat300(const float* __restrict__ x, long ldx,
                         const float* __restrict__ sA, const float* __restrict__ sB,
                         const float* __restrict__ rsc,
                         const int* __restrict__ jp, const int* __restrict__ relp,
                         const int* __restrict__ rowptr, const int* __restrict__ cnt,
                         float* __restrict__ out, long ldo, int n)
{
    int w = (blockIdx.x*blockDim.x + threadIdx.x) >> 6;
    int lane = threadIdx.x & 63;
    if (w >= n) return;
    int beg = rowptr[w], c = cnt[w];
    const int i0 = lane, i1 = lane + 64, i2 = lane + 128;
    const bool t3 = (lane < 22);
    float2 a0 = {0,0}, a1 = {0,0}, a2 = {0,0};
    if (c > 0) {
        float base = sA[w];
        int   jc = 0;
        float sval = -3.4e38f;
        if (lane < c) {
            jc = jp[beg + lane];
            sval = leaky(base + sB[jc] + rsc[relp[beg + lane]]);
        }
        float mx = sval;
        for (int t = 64 + lane; t < c; t += 64)
            mx = fmaxf(mx, leaky(base + sB[jp[beg+t]] + rsc[relp[beg+t]]));
        #pragma unroll
        for (int o = 32; o > 0; o >>= 1) mx = fmaxf(mx, __shfl_xor(mx, o));
        float pexp = (lane < c) ? expf(sval - mx) : 0.0f;
        float ss = pexp;
        for (int t = 64 + lane; t < c; t += 64)
            ss += expf(leaky(base + sB[jp[beg+t]] + rsc[relp[beg+t]]) - mx);
        #pragma unroll
        for (int o = 32; o > 0; o >>= 1) ss += __shfl_xor(ss, o);
        float inv = 1.0f / (ss + 1e-16f);
        int q = 0;
        int cc = (c < 64) ? c : 64;
        for (; q + 4 <= cc; q += 4) {
            float al0 = __shfl(pexp, q)   * inv;
            float al1 = __shfl(pexp, q+1) * inv;
            float al2 = __shfl(pexp, q+2) * inv;
            float al3 = __shfl(pexp, q+3) * inv;
            long  j0 = __shfl(jc, q), j1 = __shfl(jc, q+1);
            long  j2 = __shfl(jc, q+2), j3 = __shfl(jc, q+3);
            const float2* r0 = (const float2*)(x + j0*ldx);
            const float2* r1 = (const float2*)(x + j1*ldx);
            const float2* r2 = (const float2*)(x + j2*ldx);
            const float2* r3 = (const float2*)(x + j3*ldx);
            float2 v;
            v = r0[i0]; a0.x += al0*v.x; a0.y += al0*v.y;
            v = r1[i0]; a0.x += al1*v.x; a0.y += al1*v.y;
            v = r2[i0]; a0.x += al2*v.x; a0.y += al2*v.y;
            v = r3[i0]; a0.x += al3*v.x; a0.y += al3*v.y;
            v = r0[i1]; a1.x += al0*v.x; a1.y += al0*v.y;
            v = r1[i1]; a1.x += al1*v.x; a1.y += al1*v.y;
            v = r2[i1]; a1.x += al2*v.x; a1.y += al2*v.y;
            v = r3[i1]; a1.x += al3*v.x; a1.y += al3*v.y;
            if (t3) {
                v = r0[i2]; a2.x += al0*v.x; a2.y += al0*v.y;
                v = r1[i2]; a2.x += al1*v.x; a2.y += al1*v.y;
                v = r2[i2]; a2.x += al2*v.x; a2.y += al2*v.y;
                v = r3[i2]; a2.x += al3*v.x; a2.y += al3*v.y;
            }
        }
        for (; q < c; ++q) {
            float al; long j0;
            if (q < 64) { al = __shfl(pexp, q) * inv; j0 = __shfl(jc, q); }
            else {
                j0 = jp[beg + q];
                al = expf(leaky(base + sB[(int)j0] + rsc[relp[beg+q]]) - mx) * inv;
            }
            const float2* r0 = (const float2*)(x + j0*ldx);
            float2 v;
            v = r0[i0]; a0.x += al*v.x; a0.y += al*v.y;
            v = r0[i1]; a1.x += al*v.x; a1.y += al*v.y;
            if (t3) { v = r0[i2]; a2.x += al*v.x; a2.y += al*v.y; }
        }
    }
    float2* dst = (float2*)(out + (long)w*ldo);
    a0.x = fmaxf(a0.x, 0.0f); a0.y = fmaxf(a0.y, 0.0f);
    a1.x = fmaxf(a1.x, 0.0f); a1.y = fmaxf(a1.y, 0.0f);
    dst[i0] = a0; dst[i1] = a1;
    if (t3) { a2.x = fmaxf(a2.x, 0.0f); a2.y = fmaxf(a2.y, 0.0f); dst[i2] = a2; }
}

// r2e: fused score = leaky(snode[w] + srel[relp]) + softmax + gather of xr (F=100)
__global__ void k_gather_rel100(const float* __restrict__ xr,
                                const float* __restrict__ snode,
                                const float* __restrict__ srel,
                                const int* __restrict__ relp,
                                const int* __restrict__ rowptr, const int* __restrict__ cnt,
                                float* __restrict__ out, long ldo, int n)
{
    int w = (blockIdx.x*blockDim.x + threadIdx.x) >> 6;
    int lane = threadIdx.x & 63;
    if (w >= n) return;
    int beg = rowptr[w], c = cnt[w];
    const bool t0 = (lane < 50);
    float2 a0 = {0,0};
    if (c > 0) {
        float base = snode[w];
        int   rc = 0;
        float sval = -3.4e38f;
        if (lane < c) {
            rc = relp[beg + lane];
            sval = leaky(base + srel[rc]);
        }
        float mx = sval;
        for (int t = 64 + lane; t < c; t += 64)
            mx = fmaxf(mx, leaky(base + srel[relp[beg+t]]));
        #pragma unroll
        for (int o = 32; o > 0; o >>= 1) mx = fmaxf(mx, __shfl_xor(mx, o));
        float pexp = (lane < c) ? expf(sval - mx) : 0.0f;
        float ss = pexp;
        for (int t = 64 + lane; t < c; t += 64)
            ss += expf(leaky(base + srel[relp[beg+t]]) - mx);
        #pragma unroll
        for (int o = 32; o > 0; o >>= 1) ss += __shfl_xor(ss, o);
        float inv = 1.0f / (ss + 1e-16f);
        int q = 0;
        int cc = (c < 64) ? c : 64;
        for (; q + 4 <= cc; q += 4) {
            float al0 = __shfl(pexp, q)   * inv;
            float al1 = __shfl(pexp, q+1) * inv;
            float al2 = __shfl(pexp, q+2) * inv;
            float al3 = __shfl(pexp, q+3) * inv;
            long r0i = __shfl(rc, q), r1i = __shfl(rc, q+1);
            long r2i = __shfl(rc, q+2), r3i = __shfl(rc, q+3);
            if (t0) {
                float2 v;
                v = ((const float2*)(xr + r0i*100))[lane]; a0.x += al0*v.x; a0.y += al0*v.y;
                v = ((const float2*)(xr + r1i*100))[lane]; a0.x += al1*v.x; a0.y += al1*v.y;
                v = ((const float2*)(xr + r2i*100))[lane]; a0.x += al2*v.x; a0.y += al2*v.y;
                v = ((const float2*)(xr + r3i*100))[lane]; a0.x += al3*v.x; a0.y += al3*v.y;
            }
        }
        for (; q < c; ++q) {
            float al; long r0i;
            if (q < 64) { al = __shfl(pexp, q) * inv; r0i = __shfl(rc, q); }
            else {
                r0i = relp[beg + q];
                al = expf(leaky(base + srel[(int)r0i]) - mx) * inv;
            }
            if (t0) {
                float2 v = ((const float2*)(xr + r0i*100))[lane];
                a0.x += al*v.x; a0.y += al*v.y;
            }
        }
    }
    if (t0) ((float2*)(out + (long)w*ldo))[lane] = a0;
}

// ---------- highway combine ----------
__global__ void k_highway(const float* __restrict__ x1, long ld1,
                          const float* __restrict__ gl, long ldg,
                          const float* __restrict__ x2, long ld2,
                          const float* __restrict__ bias,
                          float* __restrict__ out, long ldo,
                          long rows, int F, int relu_x2)
{
    long idx = (long)blockIdx.x*blockDim.x + threadIdx.x;
    if (idx >= rows * (long)F) return;
    long r = idx / F; int c = (int)(idx % F);
    float g = 1.0f / (1.0f + expf(-(gl[r*ldg+c] + bias[c])));
    float v2 = x2[r*ld2+c]; if (relu_x2) v2 = fmaxf(v2, 0.0f);
    float v1 = x1[r*ld1+c];
    out[r*ldo+c] = g*v2 + (1.0f-g)*v1;
}

// ---------- segment softmax building blocks (small l_gat path only) ----------
__global__ void k_segmax(const float* __restrict__ ev, const int* __restrict__ idx,
                         unsigned* __restrict__ m, int E) {
    int e = blockIdx.x*blockDim.x + threadIdx.x;
    if (e < E) atomicMax(&m[idx[e]], f2mono(ev[e]));
}
__global__ void k_segsumexp(const float* __restrict__ ev, const int* __restrict__ idx,
                            const unsigned* __restrict__ m, float* __restrict__ s, int E) {
    int e = blockIdx.x*blockDim.x + threadIdx.x;
    if (e < E) atomicAdd(&s[idx[e]], expf(ev[e] - mono2f(m[idx[e]])));
}
__global__ void k_lgat_vsum(const float* __restrict__ val,
                            const int* __restrict__ jj, const int* __restrict__ ii,
                            const unsigned* __restrict__ mi, const float* __restrict__ si,
                            const unsigned* __restrict__ mj, const float* __restrict__ sj,
                            float* __restrict__ vsum, int E)
{
    int e = blockIdx.x*blockDim.x + threadIdx.x;
    if (e >= E) return;
    float v = val[e];
    int i = ii[e], j = jj[e];
    float pi = expf(v - mono2f(mi[i])) / (si[i] + 1e-16f);
    float pj = expf(v - mono2f(mj[j])) / (sj[j] + 1e-16f);
    vsum[e] = pi + pj;
}
__global__ void k_edge_agg(const float* __restrict__ ev,
                           const unsigned* __restrict__ m, const float* __restrict__ s,
                           const int* __restrict__ ka, const int* __restrict__ ko,
                           const int* __restrict__ ks,
                           const float* __restrict__ x, long ldx,
                           float* __restrict__ out, long ldo,
                           int E, int F)
{
    int w = (blockIdx.x*blockDim.x + threadIdx.x) >> 6;
    int lane = threadIdx.x & 63;
    if (w >= E) return;
    int a = ka[w];
    float alpha = expf(ev[w] - mono2f(m[a])) / (s[a] + 1e-16f);
    const float4* src = (const float4*)(x + (long)ks[w]*ldx);
    float* dst = out + (long)ko[w]*ldo;
    int nf4 = F >> 2;
    for (int f = lane; f < nf4; f += WAVE) {
        float4 v = src[f];
        atomicAdd(&dst[f*4+0], alpha*v.x);
        atomicAdd(&dst[f*4+1], alpha*v.y);
        atomicAdd(&dst[f*4+2], alpha*v.z);
        atomicAdd(&dst[f*4+3], alpha*v.w);
    }
}
__global__ void k_relu2d(float* __restrict__ p, long rows, int cols, long ld) {
    long idx = (long)blockIdx.x*blockDim.x + threadIdx.x;
    if (idx >= rows*(long)cols) return;
    long r = idx / cols; int c = (int)(idx % cols);
    float v = p[r*ld+c];
    p[r*ld+c] = fmaxf(v, 0.0f);
}

// ---------- row dots ----------
__global__ void k_rowdot2(const float* __restrict__ x, long ldx, int rows, int K,
                          const float* __restrict__ a, const float* __restrict__ b,
                          float* __restrict__ oa, float* __restrict__ ob)
{
    int w = (blockIdx.x*blockDim.x + threadIdx.x) >> 6;
    int lane = threadIdx.x & 63;
    if (w >= rows) return;
    const float* xr = x + (long)w*ldx;
    float sa = 0.0f, sb = 0.0f;
    for (int k = lane; k < K; k += WAVE) {
        float v = xr[k];
        sa += v * a[k];
        if (b) sb += v * b[k];
    }
    #pragma unroll
    for (int off = 32; off > 0; off >>= 1) {
        sa += __shfl_down(sa, off);
        if (b) sb += __shfl_down(sb, off);
    }
    if (lane == 0) { oa[w] = sa; if (ob) ob[w] = sb; }
}

// ---------- relscore[r] = merge[r]·ar[0:RH] + tri[r]·ar[RH:2RH] ----------
__global__ void k_relscore(const float* __restrict__ mg, const float* __restrict__ tr,
                           const float* __restrict__ ar, float* __restrict__ out, int R, int RH)
{
    int w = (blockIdx.x*blockDim.x + threadIdx.x) >> 6;
    int lane = threadIdx.x & 63;
    if (w >= R) return;
    float s = 0.0f;
    for (int k = lane; k < RH; k += WAVE)
        s += mg[(long)w*RH+k]*ar[k] + tr[(long)w*RH+k]*ar[RH+k];
    #pragma unroll
    for (int off = 32; off > 0; off >>= 1) s += __shfl_down(s, off);
    if (lane == 0) out[w] = s;
}

extern "C" void kernel_launch(void* const* d_in, const int* in_sizes, int n_in,
                              void* d_out, int out_size, void* d_ws, size_t ws_size,
                              hipStream_t stream)
{
    const float* x_e   = (const float*)d_in[0];
    const float* mval  = (const float*)d_in[1];
    const float* tval  = (const float*)d_in[2];
    const float* g1w   = (const float*)d_in[3];
    const float* h1w   = (const float*)d_in[4];
    const float* h1b   = (const float*)d_in[5];
    const float* g2w   = (const float*)d_in[6];
    const float* h2w   = (const float*)d_in[7];
    const float* h2b   = (const float*)d_in[8];
    const float* remb1 = (const float*)d_in[9];
    const float* remb2 = (const float*)d_in[10];
    const float* hrw   = (const float*)d_in[11];
    const float* hrb   = (const float*)d_in[12];
    const float* gat_ai= (const float*)d_in[13];
    const float* gat_aj= (const float*)d_in[14];
    const float* gat_ar= (const float*)d_in[15];
    const float* g2e_ah= (const float*)d_in[16];
    const float* g2e_at= (const float*)d_in[17];
    const float* g2e_ar= (const float*)d_in[18];
    const int* edge_index     = (const int*)d_in[19];
    const int* rel            = (const int*)d_in[20];
    const int* edge_index_all = (const int*)d_in[21];
    const int* rel_all        = (const int*)d_in[22];
    const int* lg_merge       = (const int*)d_in[23];
    const int* lg_tri         = (const int*)d_in[24];

    const int F    = 300;
    const int RH   = 100;
    const int N    = in_sizes[0] / F;      // 100000
    const int E    = in_sizes[20];         // 400000
    const int EA   = in_sizes[22];         // 800000
    const int LGE  = in_sizes[1];          // 60000
    const int R    = in_sizes[9] / RH;     // 2000
    const long OUTC = 800;

    const int* jA = edge_index_all;
    const int* iA = edge_index_all + EA;
    const int* hE = edge_index;
    const int* tE = edge_index + E;
    const int* jM = lg_merge;  const int* iM = lg_merge + LGE;
    const int* jT = lg_tri;    const int* iT = lg_tri  + LGE;

    float* ws = (float*)d_ws;
    size_t off = 0;
    auto alloc = [&](size_t n) { float* p = ws + off; off += (n + 1) & ~(size_t)1; return p; };
    float*    A    = alloc((size_t)N*F);
    float*    dinv = alloc(N);
    float*    sA_  = alloc(N);
    float*    sB_  = alloc(N);
    float*    mrg  = alloc((size_t)R*RH);
    float*    tri  = alloc((size_t)R*RH);
    float*    xr   = alloc((size_t)R*RH);
    float*    xrg  = alloc((size_t)R*RH);
    unsigned* lmi  = (unsigned*)alloc(R);  float* lsi = alloc(R);
    unsigned* lmj  = (unsigned*)alloc(R);  float* lsj = alloc(R);
    unsigned* lm2  = (unsigned*)alloc(R);  float* ls2 = alloc(R);
    float*    vsum = alloc(LGE);
    float*    rsc  = alloc(R);
    float*    srel = alloc(R);
    int*   bsum    = (int*)alloc(1024);
    int*   cursor  = (int*)alloc(N);
    int*   rowptrA = (int*)alloc(N); int* cntA = (int*)alloc(N); int* permA = (int*)alloc(EA);
    int*   rowptrH = (int*)alloc(N); int* cntH = (int*)alloc(N); int* permH = (int*)alloc(E);
    int*   rowptrT = (int*)alloc(N); int* cntT = (int*)alloc(N); int* permT = (int*)alloc(E);
    int*   jpA     = (int*)alloc(EA);
    float* nmA     = alloc(EA);
    int*   relpA   = (int*)alloc(EA);
    int*   relpH   = (int*)alloc(E);
    int*   relpT   = (int*)alloc(E);

    float* out = (float*)d_out;              // [N, 800]

    const long NF = (long)N * F;
    const int  nb = CDIV(N, 256);
    const int gemmGrid = CDIV(N, 128);       // 782 blocks, full-N tiles
    const int gatherGrid = CDIV(N, 4);

    auto build_csr = [&](const int* key, int E_, int* rowptr, int* cnt, int* perm) {
        hipMemsetAsync(cnt, 0, (size_t)N*4, stream);
        k_hist<<<CDIV(E_,256),256,0,stream>>>(key, cnt, E_);
        k_scan1<<<nb,256,0,stream>>>(cnt, rowptr, bsum, N);
        k_scan2<<<1,1024,0,stream>>>(bsum, nb);
        k_scan3<<<nb,256,0,stream>>>(rowptr, bsum, N);
        hipMemsetAsync(cursor, 0, (size_t)N*4, stream);
        k_fill<<<CDIV(E_,256),256,0,stream>>>(key, rowptr, cursor, perm, E_);
    };

    // ===== CSRs + pre-permutes =====
    build_csr(iA, EA, rowptrA, cntA, permA);
    build_csr(hE, E,  rowptrH, cntH, permH);
    build_csr(tE, E,  rowptrT, cntT, permT);
    k_dinv_cnt<<<CDIV(N,256),256,0,stream>>>(cntA, dinv, N);
    k_prep_gcn<<<CDIV(EA,256),256,0,stream>>>(permA, jA, iA, dinv, jpA, nmA, EA);
    k_permute_mod<<<CDIV(EA,256),256,0,stream>>>(rel_all, permA, relpA, EA, R);
    k_permute_i32<<<CDIV(E,256),256,0,stream>>>(rel, permH, relpH, E);
    k_permute_i32<<<CDIV(E,256),256,0,stream>>>(rel, permT, relpT, E);

    // ===== GCN layer 1 + highway =====
    k_gemm300<<<gemmGrid,512,0,stream>>>(x_e, F, g1w, F, A, F, N, F, F);
    k_gather300<<<gatherGrid,256,0,stream>>>(A, F, jpA, nmA, rowptrA, cntA, out+300, OUTC, N);
    k_gemm300<<<gemmGrid,512,0,stream>>>(x_e, F, h1w, F, A, F, N, F, F);
    k_highway<<<CDIV(NF,256),256,0,stream>>>(x_e, F, A, F, out+300, OUTC, h1b, out, OUTC, N, F, 1);

    // ===== GCN layer 2 + highway =====
    k_gemm300<<<gemmGrid,512,0,stream>>>(out, OUTC, g2w, F, A, F, N, F, F);
    k_gather300<<<gatherGrid,256,0,stream>>>(A, F, jpA, nmA, rowptrA, cntA, out+300, OUTC, N);
    k_gemm300<<<gemmGrid,512,0,stream>>>(out, OUTC, h2w, F, A, F, N, F, F);
    k_highway<<<CDIV(NF,256),256,0,stream>>>(out, OUTC, A, F, out+300, OUTC, h2b, out, OUTC, N, F, 1);

    // ===== l_gat on the two line graphs (small; atomic path) =====
    auto lgat = [&](const float* xrel, const int* jjE, const int* iiE, const float* val, float* obuf) {
        hipMemsetAsync(lmi, 0, R*4, stream); hipMemsetAsync(lsi, 0, R*4, stream);
        hipMemsetAsync(lmj, 0, R*4, stream); hipMemsetAsync(lsj, 0, R*4, stream);
        hipMemsetAsync(lm2, 0, R*4, stream); hipMemsetAsync(ls2, 0, R*4, stream);
        hipMemsetAsync(obuf, 0, (size_t)R*RH*4, stream);
        k_segmax   <<<CDIV(LGE,256),256,0,stream>>>(val, iiE, lmi, LGE);
        k_segmax   <<<CDIV(LGE,256),256,0,stream>>>(val, jjE, lmj, LGE);
        k_segsumexp<<<CDIV(LGE,256),256,0,stream>>>(val, iiE, lmi, lsi, LGE);
        k_segsumexp<<<CDIV(LGE,256),256,0,stream>>>(val, jjE, lmj, lsj, LGE);
        k_lgat_vsum<<<CDIV(LGE,256),256,0,stream>>>(val, jjE, iiE, lmi, lsi, lmj, lsj, vsum, LGE);
        k_segmax   <<<CDIV(LGE,256),256,0,stream>>>(vsum, jjE, lm2, LGE);
        k_segsumexp<<<CDIV(LGE,256),256,0,stream>>>(vsum, jjE, lm2, ls2, LGE);
        k_edge_agg <<<(int)CDIV((long)LGE*64,256),256,0,stream>>>(vsum, lm2, ls2, jjE, iiE, jjE,
                                                                  xrel, RH, obuf, RH, LGE, RH);
        k_relu2d   <<<CDIV((long)R*RH,256),256,0,stream>>>(obuf, R, RH, RH);
    };
    lgat(remb1, jM, iM, mval, mrg);
    lgat(remb2, jT, iT, tval, tri);

    // ===== x_r = highway(mrg, tri, hrw, hrb) =====
    dim3 gridR(CDIV(RH,GBN), CDIV(R,GBM));
    k_gemm<<<gridR,256,0,stream>>>(mrg, RH, hrw, RH, xrg, RH, R, RH, RH);
    k_highway<<<CDIV((long)R*RH,256),256,0,stream>>>(mrg, RH, xrg, RH, tri, RH, hrb, xr, RH, R, RH, 0);

    // relscore[r] = rel_cat[r]·gat_ar
    k_relscore<<<CDIV((long)R*64,256),256,0,stream>>>(mrg, tri, gat_ar, rsc, R, RH);

    // ===== GAT over edge_index_all -> out cols 300..599 (fully fused) =====
    k_rowdot2<<<CDIV((long)N*64,256),256,0,stream>>>(out, OUTC, N, F, gat_ai, gat_aj, sA_, sB_);
    k_gat300<<<gatherGrid,256,0,stream>>>(out, OUTC, sA_, sB_, rsc, jpA, relpA,
                                          rowptrA, cntA, out+300, OUTC, N);

    // ===== gat_r_to_e over edge_index -> out cols 600..799 (fully fused) =====
    k_rowdot2<<<CDIV((long)N*64,256),256,0,stream>>>(out, OUTC, N, 2*F, g2e_ah, g2e_at, sA_, sB_);
    k_rowdot2<<<CDIV((long)R*64,256),256,0,stream>>>(xr, RH, R, RH, g2e_ar, (const float*)nullptr,
                                                     srel, (float*)nullptr);
    k_gather_rel100<<<gatherGrid,256,0,stream>>>(xr, sA_, srel, relpH, rowptrH, cntH,
                                                 out+600, OUTC, N);
    k_gather_rel100<<<gatherGrid,256,0,stream>>>(xr, sB_, srel, relpT, rowptrT, cntT,
                                                 out+700, OUTC, N);
}